// Round 6
// baseline (672.184 us; speedup 1.0000x reference)
//
#include <hip/hip_runtime.h>
#include <cstdint>
#include <cstddef>

#define DF 128      // feature dim
#define HATT 64     // attention hidden dim
#define SL 4        // edge slices for graph prep
#define RPB 320     // max rows per range-block (LDS counters)

static inline int divup(int a, int b) { return (a + b - 1) / b; }

struct U16x4 { unsigned short x, y, z, w; };
typedef int vint4 __attribute__((ext_vector_type(4)));   // nontemporal-compatible

// ---------------- graph prep: 2-level (row-range x edge-slice) ----------------
// hist2: block (rb,s) counts rows [lo,hi) within edge slice s -> cnt2[s*N + r]
__global__ __launch_bounds__(256) void hist2_kernel(const int* __restrict__ row,
                                                    int* __restrict__ cnt2,
                                                    int E, int n, int ranges, int rpb, int es) {
    int rb = blockIdx.x % ranges;
    int s  = blockIdx.x / ranges;
    int lo = rb * rpb, hi = min(lo + rpb, n);
    int rows = hi - lo;
    __shared__ int lc[RPB];
    for (int j = threadIdx.x; j < rows; j += 256) lc[j] = 0;
    __syncthreads();
    int i0 = s * es, i1 = min(i0 + es, E);
    const vint4* rv = (const vint4*)row;
    for (int j = i0 / 4 + threadIdx.x; j < i1 / 4; j += 256) {
        vint4 r4 = __builtin_nontemporal_load(rv + j);
        if (r4.x >= lo && r4.x < hi) atomicAdd(&lc[r4.x - lo], 1);
        if (r4.y >= lo && r4.y < hi) atomicAdd(&lc[r4.y - lo], 1);
        if (r4.z >= lo && r4.z < hi) atomicAdd(&lc[r4.z - lo], 1);
        if (r4.w >= lo && r4.w < hi) atomicAdd(&lc[r4.w - lo], 1);
    }
    __syncthreads();
    for (int j = threadIdx.x; j < rows; j += 256) cnt2[s * n + lo + j] = lc[j];
}

// scan2: rowptr from totals; rewrite cnt2 to absolute write bases per (slice,row)
__global__ __launch_bounds__(1024) void scan2_kernel(int* __restrict__ cnt2,
                                                     int* __restrict__ row_ptr, int n) {
    __shared__ int sums[1024];
    int t = threadIdx.x;
    int chunk = (n + 1023) >> 10;
    int start = t * chunk, end = min(start + chunk, n);
    int s = 0;
    for (int r = start; r < end; ++r) {
        int tot = 0;
        for (int sl = 0; sl < SL; ++sl) tot += cnt2[sl * n + r];
        s += tot;
    }
    sums[t] = s;
    __syncthreads();
    for (int off = 1; off < 1024; off <<= 1) {
        int v = (t >= off) ? sums[t - off] : 0;
        __syncthreads();
        sums[t] += v;
        __syncthreads();
    }
    int run = sums[t] - s;  // exclusive prefix
    for (int r = start; r < end; ++r) {
        row_ptr[r] = run;
        int b = run;
        for (int sl = 0; sl < SL; ++sl) {
            int tv = cnt2[sl * n + r];
            cnt2[sl * n + r] = b;
            b += tv;
        }
        run = b;
    }
    if (t == 1023) row_ptr[n] = sums[1023];
}

// scatter2: block (rb,s) writes its rows' slice entries into their CSR segment
__global__ __launch_bounds__(256) void scatter2_kernel(const int* __restrict__ row,
                                                       const int* __restrict__ col,
                                                       const int* __restrict__ cnt2,
                                                       unsigned short* __restrict__ col_s,
                                                       int E, int n, int ranges, int rpb, int es) {
    int rb = blockIdx.x % ranges;
    int s  = blockIdx.x / ranges;
    int lo = rb * rpb, hi = min(lo + rpb, n);
    int rows = hi - lo;
    __shared__ int cur[RPB];
    for (int j = threadIdx.x; j < rows; j += 256) cur[j] = cnt2[s * n + lo + j];
    __syncthreads();
    int i0 = s * es, i1 = min(i0 + es, E);
    const vint4* rv = (const vint4*)row;
    const vint4* cv = (const vint4*)col;
    for (int j = i0 / 4 + threadIdx.x; j < i1 / 4; j += 256) {
        vint4 r4 = __builtin_nontemporal_load(rv + j);
        bool b0 = (r4.x >= lo && r4.x < hi);
        bool b1 = (r4.y >= lo && r4.y < hi);
        bool b2 = (r4.z >= lo && r4.z < hi);
        bool b3 = (r4.w >= lo && r4.w < hi);
        if (b0 | b1 | b2 | b3) {
            vint4 c4 = __builtin_nontemporal_load(cv + j);
            if (b0) { int p = atomicAdd(&cur[r4.x - lo], 1); col_s[p] = (unsigned short)c4.x; }
            if (b1) { int p = atomicAdd(&cur[r4.y - lo], 1); col_s[p] = (unsigned short)c4.y; }
            if (b2) { int p = atomicAdd(&cur[r4.z - lo], 1); col_s[p] = (unsigned short)c4.z; }
            if (b3) { int p = atomicAdd(&cur[r4.w - lo], 1); col_s[p] = (unsigned short)c4.w; }
        }
    }
}

// ---------------- split x into two 64-feature halves + squared norms ----------------

__global__ __launch_bounds__(256) void split_x_kernel(const float* __restrict__ x,
                                                      float* __restrict__ xA,
                                                      float* __restrict__ xB,
                                                      float* __restrict__ sqn, int n) {
    int wid = (blockIdx.x * blockDim.x + threadIdx.x) >> 6;
    int lane = threadIdx.x & 63;
    if (wid >= n) return;
    float v0 = x[(size_t)wid * DF + lane];
    float v1 = x[(size_t)wid * DF + 64 + lane];
    xA[(size_t)wid * 64 + lane] = v0;
    xB[(size_t)wid * 64 + lane] = v1;
    float s = v0 * v0 + v1 * v1;
    for (int off = 32; off; off >>= 1) s += __shfl_xor(s, off);
    if (lane == 0) sqn[wid] = s;
}

// ---------------- edge weights: chunk-preload + shfl broadcast ----------------
// 16 lanes per edge, 4 groups; group g at iter it handles chunk slot idx=it*4+g.
__global__ __launch_bounds__(256) void edgewA_kernel(const float* __restrict__ tA,
                                                     const unsigned short* __restrict__ col_s,
                                                     const int* __restrict__ row_ptr,
                                                     float* __restrict__ dpart, int n) {
    int wid = (blockIdx.x * blockDim.x + threadIdx.x) >> 6;
    int lane = threadIdx.x & 63;
    if (wid >= n) return;
    int sub = lane & 15, g = lane >> 4;
    int s = row_ptr[wid], e = row_ptr[wid + 1];
    float4 a = ((const float4*)(tA + (size_t)wid * 64))[sub];
    for (int base = s; base < e; base += 64) {
        int m = e - base; if (m > 64) m = 64;
        int cc = 0;
        if (lane < m) cc = (int)__builtin_nontemporal_load(col_s + base + lane);
#pragma unroll
        for (int it = 0; it < 16; ++it) {
            int idx = it * 4 + g;
            int c = __shfl(cc, idx);
            if (idx < m) {
                float4 b = ((const float4*)(tA + (size_t)c * 64))[sub];
                float d = a.x * b.x + a.y * b.y + a.z * b.z + a.w * b.w;
                d += __shfl_xor(d, 8);
                d += __shfl_xor(d, 4);
                d += __shfl_xor(d, 2);
                d += __shfl_xor(d, 1);
                if (sub == 0) __builtin_nontemporal_store(d, dpart + base + idx);
            }
        }
    }
}

// METRIC: 0 = both (wA=cos->disA, wB=euc->disB), 1 = cos only, 2 = euc only
template <int METRIC>
__global__ __launch_bounds__(256) void edgewB_kernel(const float* __restrict__ tB,
                                                     const float* __restrict__ sqn,
                                                     const unsigned short* __restrict__ col_s,
                                                     const int* __restrict__ row_ptr,
                                                     const float* __restrict__ dpart,
                                                     float* __restrict__ wA,
                                                     float* __restrict__ wB,
                                                     float* __restrict__ disA,
                                                     float* __restrict__ disB, int n) {
    int wid = (blockIdx.x * blockDim.x + threadIdx.x) >> 6;
    int lane = threadIdx.x & 63;
    if (wid >= n) return;
    int sub = lane & 15, g = lane >> 4;
    int s = row_ptr[wid], e = row_ptr[wid + 1];
    float4 a = ((const float4*)(tB + (size_t)wid * 64))[sub];
    float na = sqn[wid];
    float accA = 0.f, accB = 0.f;
    for (int base = s; base < e; base += 64) {
        int m = e - base; if (m > 64) m = 64;
        int cc = 0; float dp = 0.f;
        if (lane < m) {
            cc = (int)__builtin_nontemporal_load(col_s + base + lane);
            dp = __builtin_nontemporal_load(dpart + base + lane);
        }
#pragma unroll
        for (int it = 0; it < 16; ++it) {
            int idx = it * 4 + g;
            int c = __shfl(cc, idx);
            float dpe = __shfl(dp, idx);
            if (idx < m) {
                float4 b = ((const float4*)(tB + (size_t)c * 64))[sub];
                float d = a.x * b.x + a.y * b.y + a.z * b.z + a.w * b.w;
                d += __shfl_xor(d, 8);
                d += __shfl_xor(d, 4);
                d += __shfl_xor(d, 2);
                d += __shfl_xor(d, 1);
                if (sub == 0) {
                    d += dpe;
                    float nb = sqn[c];
                    if (METRIC != 2) {
                        float cw = d / fmaxf(sqrtf(na * nb), 1e-8f);
                        __builtin_nontemporal_store(cw, wA + base + idx);
                        accA += cw;
                    }
                    if (METRIC == 0) {
                        float ew = sqrtf(fmaxf(na + nb - 2.f * d, 0.f) + 1e-12f);
                        __builtin_nontemporal_store(ew, wB + base + idx);
                        accB += ew;
                    }
                    if (METRIC == 2) {
                        float ew = sqrtf(fmaxf(na + nb - 2.f * d, 0.f) + 1e-12f);
                        __builtin_nontemporal_store(ew, wA + base + idx);
                        accA += ew;
                    }
                }
            }
        }
    }
    accA += __shfl_xor(accA, 32);
    accA += __shfl_xor(accA, 16);
    if (METRIC == 0) {
        accB += __shfl_xor(accB, 32);
        accB += __shfl_xor(accB, 16);
    }
    if (lane == 0) {
        float dA = 1.f + accA;
        disA[wid] = (dA > 0.f) ? rsqrtf(fmaxf(dA, 1e-12f)) : 0.f;
        if (METRIC == 0) {
            float dB = 1.f + accB;
            disB[wid] = (dB > 0.f) ? rsqrtf(fmaxf(dB, 1e-12f)) : 0.f;
        }
    }
}

// ---------------- pre-scale edge weights by dis[col] (in place) ----------------
__global__ __launch_bounds__(256) void scale_wd_kernel(float* __restrict__ wsA,
                                                       float* __restrict__ wsB,
                                                       const unsigned short* __restrict__ col_s,
                                                       const float* __restrict__ disA,
                                                       const float* __restrict__ disB, int E4) {
    int j = blockIdx.x * 256 + threadIdx.x;
    if (j >= E4) return;
    U16x4 c4 = ((const U16x4*)col_s)[j];
    float4 wa = ((const float4*)wsA)[j];
    float4 wb = ((const float4*)wsB)[j];
    wa.x *= disA[c4.x]; wa.y *= disA[c4.y]; wa.z *= disA[c4.z]; wa.w *= disA[c4.w];
    wb.x *= disB[c4.x]; wb.y *= disB[c4.y]; wb.z *= disB[c4.z]; wb.w *= disB[c4.w];
    ((float4*)wsA)[j] = wa;
    ((float4*)wsB)[j] = wb;
}

// ---------------- dense matmul h = xin @ W, split in/out ----------------
__global__ __launch_bounds__(256) void mm_kernel(const float* __restrict__ inA,
                                                 const float* __restrict__ inB,
                                                 int strideIn,
                                                 const float* __restrict__ W,
                                                 float* __restrict__ hA,
                                                 float* __restrict__ hB, int n) {
    int wid = (blockIdx.x * blockDim.x + threadIdx.x) >> 6;
    int lane = threadIdx.x & 63;
    int i0 = wid * 4;
    if (i0 >= n) return;
    float v0[4], v1[4];
#pragma unroll
    for (int r = 0; r < 4; ++r) {
        int i = i0 + r;
        if (i < n) {
            v0[r] = inA[(size_t)i * strideIn + lane];
            v1[r] = inB[(size_t)i * strideIn + lane];
        } else {
            v0[r] = 0.f; v1[r] = 0.f;
        }
    }
    float acc0[4] = {0.f, 0.f, 0.f, 0.f};
    float acc1[4] = {0.f, 0.f, 0.f, 0.f};
#pragma unroll 4
    for (int k = 0; k < 64; ++k) {
        float w0 = W[k * DF + lane];
        float w1 = W[k * DF + 64 + lane];
#pragma unroll
        for (int r = 0; r < 4; ++r) {
            float a = __shfl(v0[r], k);
            acc0[r] = fmaf(a, w0, acc0[r]);
            acc1[r] = fmaf(a, w1, acc1[r]);
        }
    }
#pragma unroll 4
    for (int k = 0; k < 64; ++k) {
        float w0 = W[(k + 64) * DF + lane];
        float w1 = W[(k + 64) * DF + 64 + lane];
#pragma unroll
        for (int r = 0; r < 4; ++r) {
            float a = __shfl(v1[r], k);
            acc0[r] = fmaf(a, w0, acc0[r]);
            acc1[r] = fmaf(a, w1, acc1[r]);
        }
    }
#pragma unroll
    for (int r = 0; r < 4; ++r) {
        int i = i0 + r;
        if (i < n) {
            hA[(size_t)i * 64 + lane] = acc0[r];
            hB[(size_t)i * 64 + lane] = acc1[r];
        }
    }
}

// ---------------- fused dual SpMM, one feature half (layer 1, relu) ----------------
__global__ __launch_bounds__(256) void spmm_dual_half(const float* __restrict__ hH,
                                                      const float* __restrict__ wdA,
                                                      const float* __restrict__ wdB,
                                                      const unsigned short* __restrict__ col_s,
                                                      const float* __restrict__ disA,
                                                      const float* __restrict__ disB,
                                                      const int* __restrict__ row_ptr,
                                                      const float* __restrict__ biasH,
                                                      float* __restrict__ x1H,
                                                      float* __restrict__ x2H,
                                                      const float* __restrict__ sq1in,
                                                      const float* __restrict__ sq2in,
                                                      float* __restrict__ sq1out,
                                                      float* __restrict__ sq2out,
                                                      int finalize, int n) {
    int wid = (blockIdx.x * blockDim.x + threadIdx.x) >> 6;
    int lane = threadIdx.x & 63;
    if (wid >= n) return;
    int sub = lane & 15, g = lane >> 4;
    int s = row_ptr[wid], e = row_ptr[wid + 1];
    float diA = disA[wid], diB = disB[wid];
    float4 aA = make_float4(0.f, 0.f, 0.f, 0.f);
    float4 aB = make_float4(0.f, 0.f, 0.f, 0.f);
    for (int base = s; base < e; base += 64) {
        int m = e - base; if (m > 64) m = 64;
        int cc = 0; float wa = 0.f, wb = 0.f;
        if (lane < m) {
            cc = (int)__builtin_nontemporal_load(col_s + base + lane);
            wa = __builtin_nontemporal_load(wdA + base + lane);
            wb = __builtin_nontemporal_load(wdB + base + lane);
        }
#pragma unroll
        for (int it = 0; it < 16; ++it) {
            int idx = it * 4 + g;
            int c = __shfl(cc, idx);
            float ceA = __shfl(wa, idx);
            float ceB = __shfl(wb, idx);
            if (idx < m) {
                float4 gv = ((const float4*)(hH + (size_t)c * 64))[sub];
                aA.x = fmaf(ceA, gv.x, aA.x);
                aA.y = fmaf(ceA, gv.y, aA.y);
                aA.z = fmaf(ceA, gv.z, aA.z);
                aA.w = fmaf(ceA, gv.w, aA.w);
                aB.x = fmaf(ceB, gv.x, aB.x);
                aB.y = fmaf(ceB, gv.y, aB.y);
                aB.z = fmaf(ceB, gv.z, aB.z);
                aB.w = fmaf(ceB, gv.w, aB.w);
            }
        }
    }
#pragma unroll
    for (int off = 16; off <= 32; off <<= 1) {
        aA.x += __shfl_xor(aA.x, off);
        aA.y += __shfl_xor(aA.y, off);
        aA.z += __shfl_xor(aA.z, off);
        aA.w += __shfl_xor(aA.w, off);
        aB.x += __shfl_xor(aB.x, off);
        aB.y += __shfl_xor(aB.y, off);
        aB.z += __shfl_xor(aB.z, off);
        aB.w += __shfl_xor(aB.w, off);
    }
    float4 hv = ((const float4*)(hH + (size_t)wid * 64))[sub];
    float4 bb = ((const float4*)biasH)[sub];
    float4 oA, oB;
    oA.x = fmaxf(diA * (aA.x + diA * hv.x) + bb.x, 0.f);
    oA.y = fmaxf(diA * (aA.y + diA * hv.y) + bb.y, 0.f);
    oA.z = fmaxf(diA * (aA.z + diA * hv.z) + bb.z, 0.f);
    oA.w = fmaxf(diA * (aA.w + diA * hv.w) + bb.w, 0.f);
    oB.x = fmaxf(diB * (aB.x + diB * hv.x) + bb.x, 0.f);
    oB.y = fmaxf(diB * (aB.y + diB * hv.y) + bb.y, 0.f);
    oB.z = fmaxf(diB * (aB.z + diB * hv.z) + bb.z, 0.f);
    oB.w = fmaxf(diB * (aB.w + diB * hv.w) + bb.w, 0.f);
    if (g == 0) {
        ((float4*)(x1H + (size_t)wid * 64))[sub] = oA;
        ((float4*)(x2H + (size_t)wid * 64))[sub] = oB;
    }
    float sA = oA.x * oA.x + oA.y * oA.y + oA.z * oA.z + oA.w * oA.w;
    float sB = oB.x * oB.x + oB.y * oB.y + oB.z * oB.z + oB.w * oB.w;
#pragma unroll
    for (int off = 8; off; off >>= 1) {
        sA += __shfl_xor(sA, off);
        sB += __shfl_xor(sB, off);
    }
    if (lane == 0) {
        float pA = finalize ? sq1in[wid] : 0.f;
        float pB = finalize ? sq2in[wid] : 0.f;
        sq1out[wid] = pA + sA;
        sq2out[wid] = pB + sB;
    }
}

// ---------------- single SpMM, one feature half (layer 2, no relu) ----------------
__global__ __launch_bounds__(256) void spmm_half(const float* __restrict__ hH,
                                                 const float* __restrict__ wd,
                                                 const unsigned short* __restrict__ col_s,
                                                 const float* __restrict__ dis,
                                                 const int* __restrict__ row_ptr,
                                                 const float* __restrict__ biasH,
                                                 float* __restrict__ xoutH, int n) {
    int wid = (blockIdx.x * blockDim.x + threadIdx.x) >> 6;
    int lane = threadIdx.x & 63;
    if (wid >= n) return;
    int sub = lane & 15, g = lane >> 4;
    int s = row_ptr[wid], e = row_ptr[wid + 1];
    float di = dis[wid];
    float4 a = make_float4(0.f, 0.f, 0.f, 0.f);
    for (int base = s; base < e; base += 64) {
        int m = e - base; if (m > 64) m = 64;
        int cc = 0; float wv = 0.f;
        if (lane < m) {
            cc = (int)__builtin_nontemporal_load(col_s + base + lane);
            wv = __builtin_nontemporal_load(wd + base + lane);
        }
#pragma unroll
        for (int it = 0; it < 16; ++it) {
            int idx = it * 4 + g;
            int c = __shfl(cc, idx);
            float ce = __shfl(wv, idx);
            if (idx < m) {
                float4 gv = ((const float4*)(hH + (size_t)c * 64))[sub];
                a.x = fmaf(ce, gv.x, a.x);
                a.y = fmaf(ce, gv.y, a.y);
                a.z = fmaf(ce, gv.z, a.z);
                a.w = fmaf(ce, gv.w, a.w);
            }
        }
    }
#pragma unroll
    for (int off = 16; off <= 32; off <<= 1) {
        a.x += __shfl_xor(a.x, off);
        a.y += __shfl_xor(a.y, off);
        a.z += __shfl_xor(a.z, off);
        a.w += __shfl_xor(a.w, off);
    }
    if (g == 0) {
        float4 hv = ((const float4*)(hH + (size_t)wid * 64))[sub];
        float4 bb = ((const float4*)biasH)[sub];
        float4 o;
        o.x = di * (a.x + di * hv.x) + bb.x;
        o.y = di * (a.y + di * hv.y) + bb.y;
        o.z = di * (a.z + di * hv.z) + bb.z;
        o.w = di * (a.w + di * hv.w) + bb.w;
        ((float4*)(xoutH + (size_t)wid * 64))[sub] = o;
    }
}

// ---------------- semantic attention fusion (split inputs) ----------------
__global__ __launch_bounds__(256) void attn_kernel(const float* __restrict__ x1A,
                                                   const float* __restrict__ x1B,
                                                   const float* __restrict__ x2A,
                                                   const float* __restrict__ x2B,
                                                   const float* __restrict__ A1,
                                                   const float* __restrict__ ab1,
                                                   const float* __restrict__ A2,
                                                   float* __restrict__ out, int n) {
    __shared__ float sA1[DF * HATT];
    __shared__ float sA2[HATT];
    __shared__ float sab[HATT];
    int tid = threadIdx.x;
    for (int i = tid; i < DF * HATT; i += 256) sA1[i] = A1[i];
    if (tid < HATT) {
        sA2[tid] = A2[tid];
        sab[tid] = ab1[tid];
    }
    __syncthreads();
    int lane = tid & 63;
    int wib = tid >> 6;
    int wid = blockIdx.x * 4 + wib;
    int nw = gridDim.x * 4;
    for (int i = wid; i < n; i += nw) {
        float u0 = x1A[(size_t)i * 64 + lane], u1 = x1B[(size_t)i * 64 + lane];
        float v0 = x2A[(size_t)i * 64 + lane], v1 = x2B[(size_t)i * 64 + lane];
        float acc1 = 0.f, acc2 = 0.f;
#pragma unroll 4
        for (int d = 0; d < 64; ++d) {
            float w = sA1[d * HATT + lane];
            acc1 = fmaf(__shfl(u0, d), w, acc1);
            acc2 = fmaf(__shfl(v0, d), w, acc2);
        }
#pragma unroll 4
        for (int d = 0; d < 64; ++d) {
            float w = sA1[(d + 64) * HATT + lane];
            acc1 = fmaf(__shfl(u1, d), w, acc1);
            acc2 = fmaf(__shfl(v1, d), w, acc2);
        }
        float t1 = tanhf(acc1 + sab[lane]) * sA2[lane];
        float t2 = tanhf(acc2 + sab[lane]) * sA2[lane];
        for (int off = 32; off; off >>= 1) {
            t1 += __shfl_xor(t1, off);
            t2 += __shfl_xor(t2, off);
        }
        float mx = fmaxf(t1, t2);
        float e1 = expf(t1 - mx), e2 = expf(t2 - mx);
        float inv = 1.f / (e1 + e2);
        float be1 = e1 * inv, be2 = e2 * inv;
        out[(size_t)i * DF + lane] = be1 * u0 + be2 * v0;
        out[(size_t)i * DF + 64 + lane] = be1 * u1 + be2 * v1;
    }
}

// ---------------- launch ----------------

extern "C" void kernel_launch(void* const* d_in, const int* in_sizes, int n_in,
                              void* d_out, int out_size, void* d_ws, size_t ws_size,
                              hipStream_t stream) {
    const float* x  = (const float*)d_in[0];
    const int* row  = (const int*)d_in[1];
    const int* col  = (const int*)d_in[2];
    const float* W1 = (const float*)d_in[3];
    const float* b1 = (const float*)d_in[4];
    const float* W2 = (const float*)d_in[5];
    const float* b2 = (const float*)d_in[6];
    const float* A1 = (const float*)d_in[7];
    const float* ab1= (const float*)d_in[8];
    const float* A2 = (const float*)d_in[9];
    const int N = in_sizes[0] / DF;
    const int E = in_sizes[1];
    float* out = (float*)d_out;

    char* p = (char*)d_ws;
    auto alloc_b = [&](size_t bytes) -> char* {
        char* r = p;
        p += (bytes + 255) & ~(size_t)255;
        return r;
    };
    float* xA   = (float*)alloc_b((size_t)N * 64 * 4);
    float* xB   = (float*)alloc_b((size_t)N * 64 * 4);
    float* hA   = (float*)alloc_b((size_t)N * 64 * 4);
    float* hB   = (float*)alloc_b((size_t)N * 64 * 4);
    float* x1A  = (float*)alloc_b((size_t)N * 64 * 4);
    float* x1B  = (float*)alloc_b((size_t)N * 64 * 4);
    float* x2A  = (float*)alloc_b((size_t)N * 64 * 4);
    float* x2B  = (float*)alloc_b((size_t)N * 64 * 4);
    float* wsA  = (float*)alloc_b((size_t)E * 4);
    float* wsB  = (float*)alloc_b((size_t)E * 4);
    float* dpart= (float*)alloc_b((size_t)E * 4);
    float* disA = (float*)alloc_b((size_t)N * 4);
    float* disB = (float*)alloc_b((size_t)N * 4);
    float* sqnx = (float*)alloc_b((size_t)N * 4);
    float* sqn1 = (float*)alloc_b((size_t)N * 4);
    float* sqn2 = (float*)alloc_b((size_t)N * 4);
    float* sq1p = (float*)alloc_b((size_t)N * 4);
    float* sq2p = (float*)alloc_b((size_t)N * 4);
    int* cnt2   = (int*)alloc_b((size_t)SL * N * 4);
    int* rowptr = (int*)alloc_b((size_t)(N + 1) * 4);
    unsigned short* col_s = (unsigned short*)alloc_b((size_t)E * 2);
    (void)ws_size; (void)n_in; (void)out_size;

    const int nodeBlocks = divup(N * 64, 256);
    const int mmBlocks   = divup(divup(N, 4), 4);
    const int ranges = divup(N, RPB);                 // 32 for N=10000
    const int rpb    = divup(N, ranges);              // <= RPB
    int es = divup(E, SL); es = (es + 3) & ~3;        // slice size, 4-aligned
    const int prepBlocks = ranges * SL;
    const int vecBlocks  = divup(E / 4, 256);

    // graph prep (no global atomics, write-localized)
    hist2_kernel<<<prepBlocks, 256, 0, stream>>>(row, cnt2, E, N, ranges, rpb, es);
    split_x_kernel<<<nodeBlocks, 256, 0, stream>>>(x, xA, xB, sqnx, N);
    scan2_kernel<<<1, 1024, 0, stream>>>(cnt2, rowptr, N);
    scatter2_kernel<<<prepBlocks, 256, 0, stream>>>(row, col, cnt2, col_s, E, N, ranges, rpb, es);

    // shared layer-1 transform
    mm_kernel<<<mmBlocks, 256, 0, stream>>>(x, x + 64, DF, W1, hA, hB, N);

    // layer-1 edge weights (cos+euc share the dot), fused degree
    edgewA_kernel<<<nodeBlocks, 256, 0, stream>>>(xA, col_s, rowptr, dpart, N);
    edgewB_kernel<0><<<nodeBlocks, 256, 0, stream>>>(xB, sqnx, col_s, rowptr, dpart,
                                                     wsA, wsB, disA, disB, N);
    scale_wd_kernel<<<vecBlocks, 256, 0, stream>>>(wsA, wsB, col_s, disA, disB, E / 4);

    // fused dual SpMM layer 1, per feature half
    spmm_dual_half<<<nodeBlocks, 256, 0, stream>>>(hA, wsA, wsB, col_s, disA, disB, rowptr,
                                                   b1, x1A, x2A, sq1p, sq2p, sq1p, sq2p, 0, N);
    spmm_dual_half<<<nodeBlocks, 256, 0, stream>>>(hB, wsA, wsB, col_s, disA, disB, rowptr,
                                                   b1 + 64, x1B, x2B, sq1p, sq2p, sqn1, sqn2, 1, N);

    // layer-2 edge weights
    edgewA_kernel<<<nodeBlocks, 256, 0, stream>>>(x1A, col_s, rowptr, dpart, N);
    edgewB_kernel<1><<<nodeBlocks, 256, 0, stream>>>(x1B, sqn1, col_s, rowptr, dpart,
                                                     wsA, nullptr, disA, nullptr, N);
    edgewA_kernel<<<nodeBlocks, 256, 0, stream>>>(x2A, col_s, rowptr, dpart, N);
    edgewB_kernel<2><<<nodeBlocks, 256, 0, stream>>>(x2B, sqn2, col_s, rowptr, dpart,
                                                     wsB, nullptr, disB, nullptr, N);
    scale_wd_kernel<<<vecBlocks, 256, 0, stream>>>(wsA, wsB, col_s, disA, disB, E / 4);

    // cosine branch layer 2
    mm_kernel<<<mmBlocks, 256, 0, stream>>>(x1A, x1B, 64, W2, hA, hB, N);
    spmm_half<<<nodeBlocks, 256, 0, stream>>>(hA, wsA, col_s, disA, rowptr, b2, x1A, N);
    spmm_half<<<nodeBlocks, 256, 0, stream>>>(hB, wsA, col_s, disA, rowptr, b2 + 64, x1B, N);

    // euclid branch layer 2
    mm_kernel<<<mmBlocks, 256, 0, stream>>>(x2A, x2B, 64, W2, hA, hB, N);
    spmm_half<<<nodeBlocks, 256, 0, stream>>>(hA, wsB, col_s, disB, rowptr, b2, x2A, N);
    spmm_half<<<nodeBlocks, 256, 0, stream>>>(hB, wsB, col_s, disB, rowptr, b2 + 64, x2B, N);

    // semantic attention fusion -> out
    attn_kernel<<<divup(N, 4), 256, 0, stream>>>(x1A, x1B, x2A, x2B, A1, ab1, A2, out, N);
}

// Round 7
// 425.133 us; speedup vs baseline: 1.5811x; 1.5811x over previous
//
#include <hip/hip_runtime.h>
#include <cstdint>
#include <cstddef>

#define DF 128      // feature dim
#define HATT 64     // attention hidden dim
#define SL 64       // edge slices for graph prep
#define RPB 1280    // max rows per range-block (LDS counters)

static inline int divup(int a, int b) { return (a + b - 1) / b; }

struct U16x4 { unsigned short x, y, z, w; };
typedef int vint4 __attribute__((ext_vector_type(4)));   // nontemporal-compatible

// ---------------- graph prep: 2-level (row-range x edge-slice) ----------------
// hist2: block (rb,s) counts rows [lo,hi) within edge slice s -> cnt2[s*N + r]
__global__ __launch_bounds__(256) void hist2_kernel(const int* __restrict__ row,
                                                    int* __restrict__ cnt2,
                                                    int E, int n, int ranges, int rpb, int es) {
    int rb = blockIdx.x % ranges;
    int s  = blockIdx.x / ranges;
    int lo = rb * rpb, hi = min(lo + rpb, n);
    int rows = hi - lo;
    __shared__ int lc[RPB];
    for (int j = threadIdx.x; j < rows; j += 256) lc[j] = 0;
    __syncthreads();
    int i0 = s * es, i1 = min(i0 + es, E);
    const vint4* rv = (const vint4*)row;
    for (int j = i0 / 4 + threadIdx.x; j < i1 / 4; j += 256) {
        vint4 r4 = __builtin_nontemporal_load(rv + j);
        if (r4.x >= lo && r4.x < hi) atomicAdd(&lc[r4.x - lo], 1);
        if (r4.y >= lo && r4.y < hi) atomicAdd(&lc[r4.y - lo], 1);
        if (r4.z >= lo && r4.z < hi) atomicAdd(&lc[r4.z - lo], 1);
        if (r4.w >= lo && r4.w < hi) atomicAdd(&lc[r4.w - lo], 1);
    }
    __syncthreads();
    for (int j = threadIdx.x; j < rows; j += 256) cnt2[(size_t)s * n + lo + j] = lc[j];
}

// scanRT: per-row exclusive prefix across the SL slices (transposed LDS tile).
// cnt2[s][r] -> relative base within row r; tot[r] = row total.
__global__ __launch_bounds__(256) void scanRT_kernel(int* __restrict__ cnt2,
                                                     int* __restrict__ tot, int n) {
    __shared__ int tile[SL][65];
    int r0 = blockIdx.x * 64;
    int w = threadIdx.x >> 6;     // wave 0..3
    int lane = threadIdx.x & 63;
    int rows = min(64, n - r0);
    for (int s = w; s < SL; s += 4) {
        int v = (lane < rows) ? cnt2[(size_t)s * n + r0 + lane] : 0;
        tile[s][lane] = v;
    }
    __syncthreads();
    int t = threadIdx.x;
    if (t < rows) {
        int run = 0;
#pragma unroll
        for (int s = 0; s < SL; ++s) {
            int v = tile[s][t];
            tile[s][t] = run;
            run += v;
        }
        tot[r0 + t] = run;
    }
    __syncthreads();
    for (int s = w; s < SL; s += 4) {
        if (lane < rows) cnt2[(size_t)s * n + r0 + lane] = tile[s][lane];
    }
}

// scanT: single block, exclusive scan of per-row totals -> row_ptr
__global__ __launch_bounds__(1024) void scanT_kernel(const int* __restrict__ tot,
                                                     int* __restrict__ row_ptr, int n) {
    __shared__ int sums[1024];
    int t = threadIdx.x;
    int chunk = (n + 1023) >> 10;
    int start = t * chunk, end = min(start + chunk, n);
    int s = 0;
    for (int r = start; r < end; ++r) s += tot[r];
    sums[t] = s;
    __syncthreads();
    for (int off = 1; off < 1024; off <<= 1) {
        int v = (t >= off) ? sums[t - off] : 0;
        __syncthreads();
        sums[t] += v;
        __syncthreads();
    }
    int run = sums[t] - s;
    for (int r = start; r < end; ++r) {
        row_ptr[r] = run;
        run += tot[r];
    }
    if (t == 1023) row_ptr[n] = sums[1023];
}

// scatter2: block (rb,s) writes its rows' slice entries into their CSR segment
__global__ __launch_bounds__(256) void scatter2_kernel(const int* __restrict__ row,
                                                       const int* __restrict__ col,
                                                       const int* __restrict__ cnt2,
                                                       const int* __restrict__ row_ptr,
                                                       unsigned short* __restrict__ col_s,
                                                       int E, int n, int ranges, int rpb, int es) {
    int rb = blockIdx.x % ranges;
    int s  = blockIdx.x / ranges;
    int lo = rb * rpb, hi = min(lo + rpb, n);
    int rows = hi - lo;
    __shared__ int cur[RPB];
    for (int j = threadIdx.x; j < rows; j += 256)
        cur[j] = cnt2[(size_t)s * n + lo + j] + row_ptr[lo + j];
    __syncthreads();
    int i0 = s * es, i1 = min(i0 + es, E);
    const vint4* rv = (const vint4*)row;
    const vint4* cv = (const vint4*)col;
    for (int j = i0 / 4 + threadIdx.x; j < i1 / 4; j += 256) {
        vint4 r4 = __builtin_nontemporal_load(rv + j);
        bool b0 = (r4.x >= lo && r4.x < hi);
        bool b1 = (r4.y >= lo && r4.y < hi);
        bool b2 = (r4.z >= lo && r4.z < hi);
        bool b3 = (r4.w >= lo && r4.w < hi);
        if (b0 | b1 | b2 | b3) {
            vint4 c4 = __builtin_nontemporal_load(cv + j);
            if (b0) { int p = atomicAdd(&cur[r4.x - lo], 1); col_s[p] = (unsigned short)c4.x; }
            if (b1) { int p = atomicAdd(&cur[r4.y - lo], 1); col_s[p] = (unsigned short)c4.y; }
            if (b2) { int p = atomicAdd(&cur[r4.z - lo], 1); col_s[p] = (unsigned short)c4.z; }
            if (b3) { int p = atomicAdd(&cur[r4.w - lo], 1); col_s[p] = (unsigned short)c4.w; }
        }
    }
}

// ---------------- split x into two 64-feature halves + squared norms ----------------

__global__ __launch_bounds__(256) void split_x_kernel(const float* __restrict__ x,
                                                      float* __restrict__ xA,
                                                      float* __restrict__ xB,
                                                      float* __restrict__ sqn, int n) {
    int wid = (blockIdx.x * blockDim.x + threadIdx.x) >> 6;
    int lane = threadIdx.x & 63;
    if (wid >= n) return;
    float v0 = x[(size_t)wid * DF + lane];
    float v1 = x[(size_t)wid * DF + 64 + lane];
    xA[(size_t)wid * 64 + lane] = v0;
    xB[(size_t)wid * 64 + lane] = v1;
    float s = v0 * v0 + v1 * v1;
    for (int off = 32; off; off >>= 1) s += __shfl_xor(s, off);
    if (lane == 0) sqn[wid] = s;
}

// ---------------- edge weights: chunk-preload + shfl broadcast ----------------
// 16 lanes per edge, 4 groups; group g at iter it handles chunk slot idx=it*4+g.
__global__ __launch_bounds__(256) void edgewA_kernel(const float* __restrict__ tA,
                                                     const unsigned short* __restrict__ col_s,
                                                     const int* __restrict__ row_ptr,
                                                     float* __restrict__ dpart, int n) {
    int wid = (blockIdx.x * blockDim.x + threadIdx.x) >> 6;
    int lane = threadIdx.x & 63;
    if (wid >= n) return;
    int sub = lane & 15, g = lane >> 4;
    int s = row_ptr[wid], e = row_ptr[wid + 1];
    float4 a = ((const float4*)(tA + (size_t)wid * 64))[sub];
    for (int base = s; base < e; base += 64) {
        int m = e - base; if (m > 64) m = 64;
        int cc = 0;
        if (lane < m) cc = (int)__builtin_nontemporal_load(col_s + base + lane);
#pragma unroll
        for (int it = 0; it < 16; ++it) {
            int idx = it * 4 + g;
            int c = __shfl(cc, idx);
            if (idx < m) {
                float4 b = ((const float4*)(tA + (size_t)c * 64))[sub];
                float d = a.x * b.x + a.y * b.y + a.z * b.z + a.w * b.w;
                d += __shfl_xor(d, 8);
                d += __shfl_xor(d, 4);
                d += __shfl_xor(d, 2);
                d += __shfl_xor(d, 1);
                if (sub == 0) __builtin_nontemporal_store(d, dpart + base + idx);
            }
        }
    }
}

// METRIC: 0 = both (wA=cos->disA, wB=euc->disB), 1 = cos only, 2 = euc only
template <int METRIC>
__global__ __launch_bounds__(256) void edgewB_kernel(const float* __restrict__ tB,
                                                     const float* __restrict__ sqn,
                                                     const unsigned short* __restrict__ col_s,
                                                     const int* __restrict__ row_ptr,
                                                     const float* __restrict__ dpart,
                                                     float* __restrict__ wA,
                                                     float* __restrict__ wB,
                                                     float* __restrict__ disA,
                                                     float* __restrict__ disB, int n) {
    int wid = (blockIdx.x * blockDim.x + threadIdx.x) >> 6;
    int lane = threadIdx.x & 63;
    if (wid >= n) return;
    int sub = lane & 15, g = lane >> 4;
    int s = row_ptr[wid], e = row_ptr[wid + 1];
    float4 a = ((const float4*)(tB + (size_t)wid * 64))[sub];
    float na = sqn[wid];
    float accA = 0.f, accB = 0.f;
    for (int base = s; base < e; base += 64) {
        int m = e - base; if (m > 64) m = 64;
        int cc = 0; float dp = 0.f;
        if (lane < m) {
            cc = (int)__builtin_nontemporal_load(col_s + base + lane);
            dp = __builtin_nontemporal_load(dpart + base + lane);
        }
#pragma unroll
        for (int it = 0; it < 16; ++it) {
            int idx = it * 4 + g;
            int c = __shfl(cc, idx);
            float dpe = __shfl(dp, idx);
            if (idx < m) {
                float4 b = ((const float4*)(tB + (size_t)c * 64))[sub];
                float d = a.x * b.x + a.y * b.y + a.z * b.z + a.w * b.w;
                d += __shfl_xor(d, 8);
                d += __shfl_xor(d, 4);
                d += __shfl_xor(d, 2);
                d += __shfl_xor(d, 1);
                if (sub == 0) {
                    d += dpe;
                    float nb = sqn[c];
                    if (METRIC != 2) {
                        float cw = d / fmaxf(sqrtf(na * nb), 1e-8f);
                        __builtin_nontemporal_store(cw, wA + base + idx);
                        accA += cw;
                    }
                    if (METRIC == 0) {
                        float ew = sqrtf(fmaxf(na + nb - 2.f * d, 0.f) + 1e-12f);
                        __builtin_nontemporal_store(ew, wB + base + idx);
                        accB += ew;
                    }
                    if (METRIC == 2) {
                        float ew = sqrtf(fmaxf(na + nb - 2.f * d, 0.f) + 1e-12f);
                        __builtin_nontemporal_store(ew, wA + base + idx);
                        accA += ew;
                    }
                }
            }
        }
    }
    accA += __shfl_xor(accA, 32);
    accA += __shfl_xor(accA, 16);
    if (METRIC == 0) {
        accB += __shfl_xor(accB, 32);
        accB += __shfl_xor(accB, 16);
    }
    if (lane == 0) {
        float dA = 1.f + accA;
        disA[wid] = (dA > 0.f) ? rsqrtf(fmaxf(dA, 1e-12f)) : 0.f;
        if (METRIC == 0) {
            float dB = 1.f + accB;
            disB[wid] = (dB > 0.f) ? rsqrtf(fmaxf(dB, 1e-12f)) : 0.f;
        }
    }
}

// ---------------- pre-scale edge weights by dis[col] (in place) ----------------
__global__ __launch_bounds__(256) void scale_wd_kernel(float* __restrict__ wsA,
                                                       float* __restrict__ wsB,
                                                       const unsigned short* __restrict__ col_s,
                                                       const float* __restrict__ disA,
                                                       const float* __restrict__ disB, int E4) {
    int j = blockIdx.x * 256 + threadIdx.x;
    if (j >= E4) return;
    U16x4 c4 = ((const U16x4*)col_s)[j];
    float4 wa = ((const float4*)wsA)[j];
    float4 wb = ((const float4*)wsB)[j];
    wa.x *= disA[c4.x]; wa.y *= disA[c4.y]; wa.z *= disA[c4.z]; wa.w *= disA[c4.w];
    wb.x *= disB[c4.x]; wb.y *= disB[c4.y]; wb.z *= disB[c4.z]; wb.w *= disB[c4.w];
    ((float4*)wsA)[j] = wa;
    ((float4*)wsB)[j] = wb;
}

// ---------------- dense matmul h = xin @ W, split in/out ----------------
__global__ __launch_bounds__(256) void mm_kernel(const float* __restrict__ inA,
                                                 const float* __restrict__ inB,
                                                 int strideIn,
                                                 const float* __restrict__ W,
                                                 float* __restrict__ hA,
                                                 float* __restrict__ hB, int n) {
    int wid = (blockIdx.x * blockDim.x + threadIdx.x) >> 6;
    int lane = threadIdx.x & 63;
    int i0 = wid * 4;
    if (i0 >= n) return;
    float v0[4], v1[4];
#pragma unroll
    for (int r = 0; r < 4; ++r) {
        int i = i0 + r;
        if (i < n) {
            v0[r] = inA[(size_t)i * strideIn + lane];
            v1[r] = inB[(size_t)i * strideIn + lane];
        } else {
            v0[r] = 0.f; v1[r] = 0.f;
        }
    }
    float acc0[4] = {0.f, 0.f, 0.f, 0.f};
    float acc1[4] = {0.f, 0.f, 0.f, 0.f};
#pragma unroll 4
    for (int k = 0; k < 64; ++k) {
        float w0 = W[k * DF + lane];
        float w1 = W[k * DF + 64 + lane];
#pragma unroll
        for (int r = 0; r < 4; ++r) {
            float a = __shfl(v0[r], k);
            acc0[r] = fmaf(a, w0, acc0[r]);
            acc1[r] = fmaf(a, w1, acc1[r]);
        }
    }
#pragma unroll 4
    for (int k = 0; k < 64; ++k) {
        float w0 = W[(k + 64) * DF + lane];
        float w1 = W[(k + 64) * DF + 64 + lane];
#pragma unroll
        for (int r = 0; r < 4; ++r) {
            float a = __shfl(v1[r], k);
            acc0[r] = fmaf(a, w0, acc0[r]);
            acc1[r] = fmaf(a, w1, acc1[r]);
        }
    }
#pragma unroll
    for (int r = 0; r < 4; ++r) {
        int i = i0 + r;
        if (i < n) {
            hA[(size_t)i * 64 + lane] = acc0[r];
            hB[(size_t)i * 64 + lane] = acc1[r];
        }
    }
}

// ---------------- fused dual SpMM, one feature half (layer 1, relu) ----------------
__global__ __launch_bounds__(256) void spmm_dual_half(const float* __restrict__ hH,
                                                      const float* __restrict__ wdA,
                                                      const float* __restrict__ wdB,
                                                      const unsigned short* __restrict__ col_s,
                                                      const float* __restrict__ disA,
                                                      const float* __restrict__ disB,
                                                      const int* __restrict__ row_ptr,
                                                      const float* __restrict__ biasH,
                                                      float* __restrict__ x1H,
                                                      float* __restrict__ x2H,
                                                      const float* __restrict__ sq1in,
                                                      const float* __restrict__ sq2in,
                                                      float* __restrict__ sq1out,
                                                      float* __restrict__ sq2out,
                                                      int finalize, int n) {
    int wid = (blockIdx.x * blockDim.x + threadIdx.x) >> 6;
    int lane = threadIdx.x & 63;
    if (wid >= n) return;
    int sub = lane & 15, g = lane >> 4;
    int s = row_ptr[wid], e = row_ptr[wid + 1];
    float diA = disA[wid], diB = disB[wid];
    float4 aA = make_float4(0.f, 0.f, 0.f, 0.f);
    float4 aB = make_float4(0.f, 0.f, 0.f, 0.f);
    for (int base = s; base < e; base += 64) {
        int m = e - base; if (m > 64) m = 64;
        int cc = 0; float wa = 0.f, wb = 0.f;
        if (lane < m) {
            cc = (int)__builtin_nontemporal_load(col_s + base + lane);
            wa = __builtin_nontemporal_load(wdA + base + lane);
            wb = __builtin_nontemporal_load(wdB + base + lane);
        }
#pragma unroll
        for (int it = 0; it < 16; ++it) {
            int idx = it * 4 + g;
            int c = __shfl(cc, idx);
            float ceA = __shfl(wa, idx);
            float ceB = __shfl(wb, idx);
            if (idx < m) {
                float4 gv = ((const float4*)(hH + (size_t)c * 64))[sub];
                aA.x = fmaf(ceA, gv.x, aA.x);
                aA.y = fmaf(ceA, gv.y, aA.y);
                aA.z = fmaf(ceA, gv.z, aA.z);
                aA.w = fmaf(ceA, gv.w, aA.w);
                aB.x = fmaf(ceB, gv.x, aB.x);
                aB.y = fmaf(ceB, gv.y, aB.y);
                aB.z = fmaf(ceB, gv.z, aB.z);
                aB.w = fmaf(ceB, gv.w, aB.w);
            }
        }
    }
#pragma unroll
    for (int off = 16; off <= 32; off <<= 1) {
        aA.x += __shfl_xor(aA.x, off);
        aA.y += __shfl_xor(aA.y, off);
        aA.z += __shfl_xor(aA.z, off);
        aA.w += __shfl_xor(aA.w, off);
        aB.x += __shfl_xor(aB.x, off);
        aB.y += __shfl_xor(aB.y, off);
        aB.z += __shfl_xor(aB.z, off);
        aB.w += __shfl_xor(aB.w, off);
    }
    float4 hv = ((const float4*)(hH + (size_t)wid * 64))[sub];
    float4 bb = ((const float4*)biasH)[sub];
    float4 oA, oB;
    oA.x = fmaxf(diA * (aA.x + diA * hv.x) + bb.x, 0.f);
    oA.y = fmaxf(diA * (aA.y + diA * hv.y) + bb.y, 0.f);
    oA.z = fmaxf(diA * (aA.z + diA * hv.z) + bb.z, 0.f);
    oA.w = fmaxf(diA * (aA.w + diA * hv.w) + bb.w, 0.f);
    oB.x = fmaxf(diB * (aB.x + diB * hv.x) + bb.x, 0.f);
    oB.y = fmaxf(diB * (aB.y + diB * hv.y) + bb.y, 0.f);
    oB.z = fmaxf(diB * (aB.z + diB * hv.z) + bb.z, 0.f);
    oB.w = fmaxf(diB * (aB.w + diB * hv.w) + bb.w, 0.f);
    if (g == 0) {
        ((float4*)(x1H + (size_t)wid * 64))[sub] = oA;
        ((float4*)(x2H + (size_t)wid * 64))[sub] = oB;
    }
    float sA = oA.x * oA.x + oA.y * oA.y + oA.z * oA.z + oA.w * oA.w;
    float sB = oB.x * oB.x + oB.y * oB.y + oB.z * oB.z + oB.w * oB.w;
#pragma unroll
    for (int off = 8; off; off >>= 1) {
        sA += __shfl_xor(sA, off);
        sB += __shfl_xor(sB, off);
    }
    if (lane == 0) {
        float pA = finalize ? sq1in[wid] : 0.f;
        float pB = finalize ? sq2in[wid] : 0.f;
        sq1out[wid] = pA + sA;
        sq2out[wid] = pB + sB;
    }
}

// ---------------- single SpMM, one feature half (layer 2, no relu) ----------------
__global__ __launch_bounds__(256) void spmm_half(const float* __restrict__ hH,
                                                 const float* __restrict__ wd,
                                                 const unsigned short* __restrict__ col_s,
                                                 const float* __restrict__ dis,
                                                 const int* __restrict__ row_ptr,
                                                 const float* __restrict__ biasH,
                                                 float* __restrict__ xoutH, int n) {
    int wid = (blockIdx.x * blockDim.x + threadIdx.x) >> 6;
    int lane = threadIdx.x & 63;
    if (wid >= n) return;
    int sub = lane & 15, g = lane >> 4;
    int s = row_ptr[wid], e = row_ptr[wid + 1];
    float di = dis[wid];
    float4 a = make_float4(0.f, 0.f, 0.f, 0.f);
    for (int base = s; base < e; base += 64) {
        int m = e - base; if (m > 64) m = 64;
        int cc = 0; float wv = 0.f;
        if (lane < m) {
            cc = (int)__builtin_nontemporal_load(col_s + base + lane);
            wv = __builtin_nontemporal_load(wd + base + lane);
        }
#pragma unroll
        for (int it = 0; it < 16; ++it) {
            int idx = it * 4 + g;
            int c = __shfl(cc, idx);
            float ce = __shfl(wv, idx);
            if (idx < m) {
                float4 gv = ((const float4*)(hH + (size_t)c * 64))[sub];
                a.x = fmaf(ce, gv.x, a.x);
                a.y = fmaf(ce, gv.y, a.y);
                a.z = fmaf(ce, gv.z, a.z);
                a.w = fmaf(ce, gv.w, a.w);
            }
        }
    }
#pragma unroll
    for (int off = 16; off <= 32; off <<= 1) {
        a.x += __shfl_xor(a.x, off);
        a.y += __shfl_xor(a.y, off);
        a.z += __shfl_xor(a.z, off);
        a.w += __shfl_xor(a.w, off);
    }
    if (g == 0) {
        float4 hv = ((const float4*)(hH + (size_t)wid * 64))[sub];
        float4 bb = ((const float4*)biasH)[sub];
        float4 o;
        o.x = di * (a.x + di * hv.x) + bb.x;
        o.y = di * (a.y + di * hv.y) + bb.y;
        o.z = di * (a.z + di * hv.z) + bb.z;
        o.w = di * (a.w + di * hv.w) + bb.w;
        ((float4*)(xoutH + (size_t)wid * 64))[sub] = o;
    }
}

// ---------------- semantic attention fusion (split inputs) ----------------
__global__ __launch_bounds__(256) void attn_kernel(const float* __restrict__ x1A,
                                                   const float* __restrict__ x1B,
                                                   const float* __restrict__ x2A,
                                                   const float* __restrict__ x2B,
                                                   const float* __restrict__ A1,
                                                   const float* __restrict__ ab1,
                                                   const float* __restrict__ A2,
                                                   float* __restrict__ out, int n) {
    __shared__ float sA1[DF * HATT];
    __shared__ float sA2[HATT];
    __shared__ float sab[HATT];
    int tid = threadIdx.x;
    for (int i = tid; i < DF * HATT; i += 256) sA1[i] = A1[i];
    if (tid < HATT) {
        sA2[tid] = A2[tid];
        sab[tid] = ab1[tid];
    }
    __syncthreads();
    int lane = tid & 63;
    int wib = tid >> 6;
    int wid = blockIdx.x * 4 + wib;
    int nw = gridDim.x * 4;
    for (int i = wid; i < n; i += nw) {
        float u0 = x1A[(size_t)i * 64 + lane], u1 = x1B[(size_t)i * 64 + lane];
        float v0 = x2A[(size_t)i * 64 + lane], v1 = x2B[(size_t)i * 64 + lane];
        float acc1 = 0.f, acc2 = 0.f;
#pragma unroll 4
        for (int d = 0; d < 64; ++d) {
            float w = sA1[d * HATT + lane];
            acc1 = fmaf(__shfl(u0, d), w, acc1);
            acc2 = fmaf(__shfl(v0, d), w, acc2);
        }
#pragma unroll 4
        for (int d = 0; d < 64; ++d) {
            float w = sA1[(d + 64) * HATT + lane];
            acc1 = fmaf(__shfl(u1, d), w, acc1);
            acc2 = fmaf(__shfl(v1, d), w, acc2);
        }
        float t1 = tanhf(acc1 + sab[lane]) * sA2[lane];
        float t2 = tanhf(acc2 + sab[lane]) * sA2[lane];
        for (int off = 32; off; off >>= 1) {
            t1 += __shfl_xor(t1, off);
            t2 += __shfl_xor(t2, off);
        }
        float mx = fmaxf(t1, t2);
        float e1 = expf(t1 - mx), e2 = expf(t2 - mx);
        float inv = 1.f / (e1 + e2);
        float be1 = e1 * inv, be2 = e2 * inv;
        out[(size_t)i * DF + lane] = be1 * u0 + be2 * v0;
        out[(size_t)i * DF + 64 + lane] = be1 * u1 + be2 * v1;
    }
}

// ---------------- launch ----------------

extern "C" void kernel_launch(void* const* d_in, const int* in_sizes, int n_in,
                              void* d_out, int out_size, void* d_ws, size_t ws_size,
                              hipStream_t stream) {
    const float* x  = (const float*)d_in[0];
    const int* row  = (const int*)d_in[1];
    const int* col  = (const int*)d_in[2];
    const float* W1 = (const float*)d_in[3];
    const float* b1 = (const float*)d_in[4];
    const float* W2 = (const float*)d_in[5];
    const float* b2 = (const float*)d_in[6];
    const float* A1 = (const float*)d_in[7];
    const float* ab1= (const float*)d_in[8];
    const float* A2 = (const float*)d_in[9];
    const int N = in_sizes[0] / DF;
    const int E = in_sizes[1];
    float* out = (float*)d_out;

    char* p = (char*)d_ws;
    auto alloc_b = [&](size_t bytes) -> char* {
        char* r = p;
        p += (bytes + 255) & ~(size_t)255;
        return r;
    };
    float* xA   = (float*)alloc_b((size_t)N * 64 * 4);
    float* xB   = (float*)alloc_b((size_t)N * 64 * 4);
    float* hA   = (float*)alloc_b((size_t)N * 64 * 4);
    float* hB   = (float*)alloc_b((size_t)N * 64 * 4);
    float* x1A  = (float*)alloc_b((size_t)N * 64 * 4);
    float* x1B  = (float*)alloc_b((size_t)N * 64 * 4);
    float* x2A  = (float*)alloc_b((size_t)N * 64 * 4);
    float* x2B  = (float*)alloc_b((size_t)N * 64 * 4);
    float* wsA  = (float*)alloc_b((size_t)E * 4);
    float* wsB  = (float*)alloc_b((size_t)E * 4);
    float* dpart= (float*)alloc_b((size_t)E * 4);
    float* disA = (float*)alloc_b((size_t)N * 4);
    float* disB = (float*)alloc_b((size_t)N * 4);
    float* sqnx = (float*)alloc_b((size_t)N * 4);
    float* sqn1 = (float*)alloc_b((size_t)N * 4);
    float* sqn2 = (float*)alloc_b((size_t)N * 4);
    float* sq1p = (float*)alloc_b((size_t)N * 4);
    float* sq2p = (float*)alloc_b((size_t)N * 4);
    int* cnt2   = (int*)alloc_b((size_t)SL * N * 4);
    int* tot    = (int*)alloc_b((size_t)N * 4);
    int* rowptr = (int*)alloc_b((size_t)(N + 1) * 4);
    unsigned short* col_s = (unsigned short*)alloc_b((size_t)E * 2);
    (void)ws_size; (void)n_in; (void)out_size;

    const int nodeBlocks = divup(N * 64, 256);
    const int mmBlocks   = divup(divup(N, 4), 4);
    const int ranges = divup(N, RPB);                 // 8 for N=10000
    const int rpb    = divup(N, ranges);              // 1250 <= RPB
    int es = divup(E, SL); es = (es + 3) & ~3;        // slice size, 4-aligned
    const int prepBlocks = ranges * SL;               // 512
    const int vecBlocks  = divup(E / 4, 256);

    // graph prep (no global atomics, write-localized, 512-block parallel)
    hist2_kernel<<<prepBlocks, 256, 0, stream>>>(row, cnt2, E, N, ranges, rpb, es);
    split_x_kernel<<<nodeBlocks, 256, 0, stream>>>(x, xA, xB, sqnx, N);
    scanRT_kernel<<<divup(N, 64), 256, 0, stream>>>(cnt2, tot, N);
    scanT_kernel<<<1, 1024, 0, stream>>>(tot, rowptr, N);
    scatter2_kernel<<<prepBlocks, 256, 0, stream>>>(row, col, cnt2, rowptr, col_s, E, N, ranges, rpb, es);

    // shared layer-1 transform
    mm_kernel<<<mmBlocks, 256, 0, stream>>>(x, x + 64, DF, W1, hA, hB, N);

    // layer-1 edge weights (cos+euc share the dot), fused degree
    edgewA_kernel<<<nodeBlocks, 256, 0, stream>>>(xA, col_s, rowptr, dpart, N);
    edgewB_kernel<0><<<nodeBlocks, 256, 0, stream>>>(xB, sqnx, col_s, rowptr, dpart,
                                                     wsA, wsB, disA, disB, N);
    scale_wd_kernel<<<vecBlocks, 256, 0, stream>>>(wsA, wsB, col_s, disA, disB, E / 4);

    // fused dual SpMM layer 1, per feature half
    spmm_dual_half<<<nodeBlocks, 256, 0, stream>>>(hA, wsA, wsB, col_s, disA, disB, rowptr,
                                                   b1, x1A, x2A, sq1p, sq2p, sq1p, sq2p, 0, N);
    spmm_dual_half<<<nodeBlocks, 256, 0, stream>>>(hB, wsA, wsB, col_s, disA, disB, rowptr,
                                                   b1 + 64, x1B, x2B, sq1p, sq2p, sqn1, sqn2, 1, N);

    // layer-2 edge weights
    edgewA_kernel<<<nodeBlocks, 256, 0, stream>>>(x1A, col_s, rowptr, dpart, N);
    edgewB_kernel<1><<<nodeBlocks, 256, 0, stream>>>(x1B, sqn1, col_s, rowptr, dpart,
                                                     wsA, nullptr, disA, nullptr, N);
    edgewA_kernel<<<nodeBlocks, 256, 0, stream>>>(x2A, col_s, rowptr, dpart, N);
    edgewB_kernel<2><<<nodeBlocks, 256, 0, stream>>>(x2B, sqn2, col_s, rowptr, dpart,
                                                     wsB, nullptr, disB, nullptr, N);
    scale_wd_kernel<<<vecBlocks, 256, 0, stream>>>(wsA, wsB, col_s, disA, disB, E / 4);

    // cosine branch layer 2
    mm_kernel<<<mmBlocks, 256, 0, stream>>>(x1A, x1B, 64, W2, hA, hB, N);
    spmm_half<<<nodeBlocks, 256, 0, stream>>>(hA, wsA, col_s, disA, rowptr, b2, x1A, N);
    spmm_half<<<nodeBlocks, 256, 0, stream>>>(hB, wsA, col_s, disA, rowptr, b2 + 64, x1B, N);

    // euclid branch layer 2
    mm_kernel<<<mmBlocks, 256, 0, stream>>>(x2A, x2B, 64, W2, hA, hB, N);
    spmm_half<<<nodeBlocks, 256, 0, stream>>>(hA, wsB, col_s, disB, rowptr, b2, x2A, N);
    spmm_half<<<nodeBlocks, 256, 0, stream>>>(hB, wsB, col_s, disB, rowptr, b2 + 64, x2B, N);

    // semantic attention fusion -> out
    attn_kernel<<<divup(N, 4), 256, 0, stream>>>(x1A, x1B, x2A, x2B, A1, ab1, A2, out, N);
}

// Round 8
// 406.625 us; speedup vs baseline: 1.6531x; 1.0455x over previous
//
#include <hip/hip_runtime.h>
#include <cstdint>
#include <cstddef>

#define DF 128      // feature dim
#define HATT 64     // attention hidden dim
#define SL 64       // edge slices for graph prep
#define RPB 1280    // max rows per range-block (LDS counters)

static inline int divup(int a, int b) { return (a + b - 1) / b; }

typedef int vint4 __attribute__((ext_vector_type(4)));   // nontemporal-compatible

// ---------------- graph prep: 2-level (row-range x edge-slice) ----------------
__global__ __launch_bounds__(256) void hist2_kernel(const int* __restrict__ row,
                                                    int* __restrict__ cnt2,
                                                    int E, int n, int ranges, int rpb, int es) {
    int rb = blockIdx.x % ranges;
    int s  = blockIdx.x / ranges;
    int lo = rb * rpb, hi = min(lo + rpb, n);
    int rows = hi - lo;
    __shared__ int lc[RPB];
    for (int j = threadIdx.x; j < rows; j += 256) lc[j] = 0;
    __syncthreads();
    int i0 = s * es, i1 = min(i0 + es, E);
    const vint4* rv = (const vint4*)row;
    for (int j = i0 / 4 + threadIdx.x; j < i1 / 4; j += 256) {
        vint4 r4 = __builtin_nontemporal_load(rv + j);
        if (r4.x >= lo && r4.x < hi) atomicAdd(&lc[r4.x - lo], 1);
        if (r4.y >= lo && r4.y < hi) atomicAdd(&lc[r4.y - lo], 1);
        if (r4.z >= lo && r4.z < hi) atomicAdd(&lc[r4.z - lo], 1);
        if (r4.w >= lo && r4.w < hi) atomicAdd(&lc[r4.w - lo], 1);
    }
    __syncthreads();
    for (int j = threadIdx.x; j < rows; j += 256) cnt2[(size_t)s * n + lo + j] = lc[j];
}

__global__ __launch_bounds__(256) void scanRT_kernel(int* __restrict__ cnt2,
                                                     int* __restrict__ tot, int n) {
    __shared__ int tile[SL][65];
    int r0 = blockIdx.x * 64;
    int w = threadIdx.x >> 6;
    int lane = threadIdx.x & 63;
    int rows = min(64, n - r0);
    for (int s = w; s < SL; s += 4) {
        int v = (lane < rows) ? cnt2[(size_t)s * n + r0 + lane] : 0;
        tile[s][lane] = v;
    }
    __syncthreads();
    int t = threadIdx.x;
    if (t < rows) {
        int run = 0;
#pragma unroll
        for (int s = 0; s < SL; ++s) {
            int v = tile[s][t];
            tile[s][t] = run;
            run += v;
        }
        tot[r0 + t] = run;
    }
    __syncthreads();
    for (int s = w; s < SL; s += 4) {
        if (lane < rows) cnt2[(size_t)s * n + r0 + lane] = tile[s][lane];
    }
}

__global__ __launch_bounds__(1024) void scanT_kernel(const int* __restrict__ tot,
                                                     int* __restrict__ row_ptr, int n) {
    __shared__ int sums[1024];
    int t = threadIdx.x;
    int chunk = (n + 1023) >> 10;
    int start = t * chunk, end = min(start + chunk, n);
    int s = 0;
    for (int r = start; r < end; ++r) s += tot[r];
    sums[t] = s;
    __syncthreads();
    for (int off = 1; off < 1024; off <<= 1) {
        int v = (t >= off) ? sums[t - off] : 0;
        __syncthreads();
        sums[t] += v;
        __syncthreads();
    }
    int run = sums[t] - s;
    for (int r = start; r < end; ++r) {
        row_ptr[r] = run;
        run += tot[r];
    }
    if (t == 1023) row_ptr[n] = sums[1023];
}

__global__ __launch_bounds__(256) void scatter2_kernel(const int* __restrict__ row,
                                                       const int* __restrict__ col,
                                                       const int* __restrict__ cnt2,
                                                       const int* __restrict__ row_ptr,
                                                       unsigned short* __restrict__ col_s,
                                                       int E, int n, int ranges, int rpb, int es) {
    int rb = blockIdx.x % ranges;
    int s  = blockIdx.x / ranges;
    int lo = rb * rpb, hi = min(lo + rpb, n);
    int rows = hi - lo;
    __shared__ int cur[RPB];
    for (int j = threadIdx.x; j < rows; j += 256)
        cur[j] = cnt2[(size_t)s * n + lo + j] + row_ptr[lo + j];
    __syncthreads();
    int i0 = s * es, i1 = min(i0 + es, E);
    const vint4* rv = (const vint4*)row;
    const vint4* cv = (const vint4*)col;
    for (int j = i0 / 4 + threadIdx.x; j < i1 / 4; j += 256) {
        vint4 r4 = __builtin_nontemporal_load(rv + j);
        bool b0 = (r4.x >= lo && r4.x < hi);
        bool b1 = (r4.y >= lo && r4.y < hi);
        bool b2 = (r4.z >= lo && r4.z < hi);
        bool b3 = (r4.w >= lo && r4.w < hi);
        if (b0 | b1 | b2 | b3) {
            vint4 c4 = __builtin_nontemporal_load(cv + j);
            if (b0) { int p = atomicAdd(&cur[r4.x - lo], 1); col_s[p] = (unsigned short)c4.x; }
            if (b1) { int p = atomicAdd(&cur[r4.y - lo], 1); col_s[p] = (unsigned short)c4.y; }
            if (b2) { int p = atomicAdd(&cur[r4.z - lo], 1); col_s[p] = (unsigned short)c4.z; }
            if (b3) { int p = atomicAdd(&cur[r4.w - lo], 1); col_s[p] = (unsigned short)c4.w; }
        }
    }
}

// ---------------- split x + squared norms ----------------
__global__ __launch_bounds__(256) void split_x_kernel(const float* __restrict__ x,
                                                      float* __restrict__ xA,
                                                      float* __restrict__ xB,
                                                      float* __restrict__ sqn, int n) {
    int wid = (blockIdx.x * blockDim.x + threadIdx.x) >> 6;
    int lane = threadIdx.x & 63;
    if (wid >= n) return;
    float v0 = x[(size_t)wid * DF + lane];
    float v1 = x[(size_t)wid * DF + 64 + lane];
    xA[(size_t)wid * 64 + lane] = v0;
    xB[(size_t)wid * 64 + lane] = v1;
    float s = v0 * v0 + v1 * v1;
    for (int off = 32; off; off >>= 1) s += __shfl_xor(s, off);
    if (lane == 0) sqn[wid] = s;
}

// ---------------- layer-1 edge weights (unpaired) ----------------
__global__ __launch_bounds__(256) void edgewA_kernel(const float* __restrict__ tA,
                                                     const unsigned short* __restrict__ col_s,
                                                     const int* __restrict__ row_ptr,
                                                     float* __restrict__ dpart, int n) {
    int wid = (blockIdx.x * blockDim.x + threadIdx.x) >> 6;
    int lane = threadIdx.x & 63;
    if (wid >= n) return;
    int sub = lane & 15, g = lane >> 4;
    int s = row_ptr[wid], e = row_ptr[wid + 1];
    float4 a = ((const float4*)(tA + (size_t)wid * 64))[sub];
    for (int base = s; base < e; base += 64) {
        int m = e - base; if (m > 64) m = 64;
        int cc = 0;
        if (lane < m) cc = (int)__builtin_nontemporal_load(col_s + base + lane);
#define EWA_BODY(CHK)                                                        \
        _Pragma("unroll")                                                    \
        for (int it = 0; it < 16; ++it) {                                    \
            int idx = it * 4 + g;                                            \
            int c = __shfl(cc, idx);                                         \
            if (CHK) {                                                       \
                float4 b = ((const float4*)(tA + (size_t)c * 64))[sub];      \
                float d = a.x * b.x + a.y * b.y + a.z * b.z + a.w * b.w;     \
                d += __shfl_xor(d, 8); d += __shfl_xor(d, 4);                \
                d += __shfl_xor(d, 2); d += __shfl_xor(d, 1);                \
                if (sub == 0) __builtin_nontemporal_store(d, dpart + base + idx); \
            }                                                                \
        }
        if (m == 64) { EWA_BODY(true) } else { EWA_BODY(idx < m) }
#undef EWA_BODY
    }
}

// layer-1 pass B: both metrics, fused degree
__global__ __launch_bounds__(256) void edgewB1_kernel(const float* __restrict__ tB,
                                                      const float* __restrict__ sqn,
                                                      const unsigned short* __restrict__ col_s,
                                                      const int* __restrict__ row_ptr,
                                                      const float* __restrict__ dpart,
                                                      float* __restrict__ wA,
                                                      float* __restrict__ wB,
                                                      float* __restrict__ disA,
                                                      float* __restrict__ disB, int n) {
    int wid = (blockIdx.x * blockDim.x + threadIdx.x) >> 6;
    int lane = threadIdx.x & 63;
    if (wid >= n) return;
    int sub = lane & 15, g = lane >> 4;
    int s = row_ptr[wid], e = row_ptr[wid + 1];
    float4 a = ((const float4*)(tB + (size_t)wid * 64))[sub];
    float na = sqn[wid];
    float accA = 0.f, accB = 0.f;
    for (int base = s; base < e; base += 64) {
        int m = e - base; if (m > 64) m = 64;
        int cc = 0; float dp = 0.f;
        if (lane < m) {
            cc = (int)__builtin_nontemporal_load(col_s + base + lane);
            dp = __builtin_nontemporal_load(dpart + base + lane);
        }
#define EWB1_BODY(CHK)                                                       \
        _Pragma("unroll")                                                    \
        for (int it = 0; it < 16; ++it) {                                    \
            int idx = it * 4 + g;                                            \
            int c = __shfl(cc, idx);                                         \
            float dpe = __shfl(dp, idx);                                     \
            if (CHK) {                                                       \
                float4 b = ((const float4*)(tB + (size_t)c * 64))[sub];      \
                float d = a.x * b.x + a.y * b.y + a.z * b.z + a.w * b.w;     \
                d += __shfl_xor(d, 8); d += __shfl_xor(d, 4);                \
                d += __shfl_xor(d, 2); d += __shfl_xor(d, 1);                \
                if (sub == 0) {                                              \
                    d += dpe;                                                \
                    float nb = sqn[c];                                       \
                    float cw = d / fmaxf(sqrtf(na * nb), 1e-8f);             \
                    __builtin_nontemporal_store(cw, wA + base + idx);        \
                    accA += cw;                                              \
                    float ew = sqrtf(fmaxf(na + nb - 2.f * d, 0.f) + 1e-12f);\
                    __builtin_nontemporal_store(ew, wB + base + idx);        \
                    accB += ew;                                              \
                }                                                            \
            }                                                                \
        }
        if (m == 64) { EWB1_BODY(true) } else { EWB1_BODY(idx < m) }
#undef EWB1_BODY
    }
    accA += __shfl_xor(accA, 32); accA += __shfl_xor(accA, 16);
    accB += __shfl_xor(accB, 32); accB += __shfl_xor(accB, 16);
    if (lane == 0) {
        float dA = 1.f + accA;
        disA[wid] = (dA > 0.f) ? rsqrtf(fmaxf(dA, 1e-12f)) : 0.f;
        float dB = 1.f + accB;
        disB[wid] = (dB > 0.f) ? rsqrtf(fmaxf(dB, 1e-12f)) : 0.f;
    }
}

// ---------------- layer-2 edge weights, paired across branches (XCD parity) ----------------
__global__ __launch_bounds__(256) void edgewA2_kernel(const float* __restrict__ t0,
                                                      const float* __restrict__ t1,
                                                      const unsigned short* __restrict__ col_s,
                                                      const int* __restrict__ row_ptr,
                                                      float* __restrict__ dp0,
                                                      float* __restrict__ dp1, int n) {
    int br = blockIdx.x & 1;
    int wid = (blockIdx.x >> 1) * 4 + (threadIdx.x >> 6);
    int lane = threadIdx.x & 63;
    if (wid >= n) return;
    const float* tA = br ? t1 : t0;
    float* dpart = br ? dp1 : dp0;
    int sub = lane & 15, g = lane >> 4;
    int s = row_ptr[wid], e = row_ptr[wid + 1];
    float4 a = ((const float4*)(tA + (size_t)wid * 64))[sub];
    for (int base = s; base < e; base += 64) {
        int m = e - base; if (m > 64) m = 64;
        int cc = 0;
        if (lane < m) cc = (int)__builtin_nontemporal_load(col_s + base + lane);
#define EWA2_BODY(CHK)                                                       \
        _Pragma("unroll")                                                    \
        for (int it = 0; it < 16; ++it) {                                    \
            int idx = it * 4 + g;                                            \
            int c = __shfl(cc, idx);                                         \
            if (CHK) {                                                       \
                float4 b = ((const float4*)(tA + (size_t)c * 64))[sub];      \
                float d = a.x * b.x + a.y * b.y + a.z * b.z + a.w * b.w;     \
                d += __shfl_xor(d, 8); d += __shfl_xor(d, 4);                \
                d += __shfl_xor(d, 2); d += __shfl_xor(d, 1);                \
                if (sub == 0) __builtin_nontemporal_store(d, dpart + base + idx); \
            }                                                                \
        }
        if (m == 64) { EWA2_BODY(true) } else { EWA2_BODY(idx < m) }
#undef EWA2_BODY
    }
}

// branch 0: cosine on x1 (norms sq1pA+sq1pB) -> wsA,disA ; branch 1: euclid on x2 -> wsB,disB
__global__ __launch_bounds__(256) void edgewB2_kernel(const float* __restrict__ t0B,
                                                      const float* __restrict__ t1B,
                                                      const float* __restrict__ sq1pA,
                                                      const float* __restrict__ sq1pB,
                                                      const float* __restrict__ sq2pA,
                                                      const float* __restrict__ sq2pB,
                                                      const unsigned short* __restrict__ col_s,
                                                      const int* __restrict__ row_ptr,
                                                      const float* __restrict__ dp0,
                                                      const float* __restrict__ dp1,
                                                      float* __restrict__ wsA,
                                                      float* __restrict__ wsB,
                                                      float* __restrict__ disA,
                                                      float* __restrict__ disB, int n) {
    int br = blockIdx.x & 1;
    int wid = (blockIdx.x >> 1) * 4 + (threadIdx.x >> 6);
    int lane = threadIdx.x & 63;
    if (wid >= n) return;
    const float* tB = br ? t1B : t0B;
    const float* sqA = br ? sq2pA : sq1pA;
    const float* sqB = br ? sq2pB : sq1pB;
    const float* dpart = br ? dp1 : dp0;
    float* wOut = br ? wsB : wsA;
    float* disOut = br ? disB : disA;
    int sub = lane & 15, g = lane >> 4;
    int s = row_ptr[wid], e = row_ptr[wid + 1];
    float4 a = ((const float4*)(tB + (size_t)wid * 64))[sub];
    float na = sqA[wid] + sqB[wid];
    float acc = 0.f;
    for (int base = s; base < e; base += 64) {
        int m = e - base; if (m > 64) m = 64;
        int cc = 0; float dp = 0.f;
        if (lane < m) {
            cc = (int)__builtin_nontemporal_load(col_s + base + lane);
            dp = __builtin_nontemporal_load(dpart + base + lane);
        }
#define EWB2_BODY(CHK)                                                       \
        _Pragma("unroll")                                                    \
        for (int it = 0; it < 16; ++it) {                                    \
            int idx = it * 4 + g;                                            \
            int c = __shfl(cc, idx);                                         \
            float dpe = __shfl(dp, idx);                                     \
            if (CHK) {                                                       \
                float4 b = ((const float4*)(tB + (size_t)c * 64))[sub];      \
                float d = a.x * b.x + a.y * b.y + a.z * b.z + a.w * b.w;     \
                d += __shfl_xor(d, 8); d += __shfl_xor(d, 4);                \
                d += __shfl_xor(d, 2); d += __shfl_xor(d, 1);                \
                if (sub == 0) {                                              \
                    d += dpe;                                                \
                    float nb = sqA[c] + sqB[c];                              \
                    float w;                                                 \
                    if (br == 0) w = d / fmaxf(sqrtf(na * nb), 1e-8f);       \
                    else w = sqrtf(fmaxf(na + nb - 2.f * d, 0.f) + 1e-12f);  \
                    __builtin_nontemporal_store(w, wOut + base + idx);       \
                    acc += w;                                                \
                }                                                            \
            }                                                                \
        }
        if (m == 64) { EWB2_BODY(true) } else { EWB2_BODY(idx < m) }
#undef EWB2_BODY
    }
    acc += __shfl_xor(acc, 32); acc += __shfl_xor(acc, 16);
    if (lane == 0) {
        float dg = 1.f + acc;
        disOut[wid] = (dg > 0.f) ? rsqrtf(fmaxf(dg, 1e-12f)) : 0.f;
    }
}

// ---------------- dense matmuls ----------------
__global__ __launch_bounds__(256) void mm_kernel(const float* __restrict__ inA,
                                                 const float* __restrict__ inB,
                                                 int strideIn,
                                                 const float* __restrict__ W,
                                                 float* __restrict__ hA,
                                                 float* __restrict__ hB, int n) {
    int wid = (blockIdx.x * blockDim.x + threadIdx.x) >> 6;
    int lane = threadIdx.x & 63;
    int i0 = wid * 4;
    if (i0 >= n) return;
    float v0[4], v1[4];
#pragma unroll
    for (int r = 0; r < 4; ++r) {
        int i = i0 + r;
        if (i < n) { v0[r] = inA[(size_t)i * strideIn + lane]; v1[r] = inB[(size_t)i * strideIn + lane]; }
        else { v0[r] = 0.f; v1[r] = 0.f; }
    }
    float acc0[4] = {0.f, 0.f, 0.f, 0.f};
    float acc1[4] = {0.f, 0.f, 0.f, 0.f};
#pragma unroll 4
    for (int k = 0; k < 64; ++k) {
        float w0 = W[k * DF + lane];
        float w1 = W[k * DF + 64 + lane];
#pragma unroll
        for (int r = 0; r < 4; ++r) {
            float a = __shfl(v0[r], k);
            acc0[r] = fmaf(a, w0, acc0[r]);
            acc1[r] = fmaf(a, w1, acc1[r]);
        }
    }
#pragma unroll 4
    for (int k = 0; k < 64; ++k) {
        float w0 = W[(k + 64) * DF + lane];
        float w1 = W[(k + 64) * DF + 64 + lane];
#pragma unroll
        for (int r = 0; r < 4; ++r) {
            float a = __shfl(v1[r], k);
            acc0[r] = fmaf(a, w0, acc0[r]);
            acc1[r] = fmaf(a, w1, acc1[r]);
        }
    }
#pragma unroll
    for (int r = 0; r < 4; ++r) {
        int i = i0 + r;
        if (i < n) { hA[(size_t)i * 64 + lane] = acc0[r]; hB[(size_t)i * 64 + lane] = acc1[r]; }
    }
}

// paired layer-2 mm: branch parity (x1@W2 on even XCDs, x2@W2 on odd)
__global__ __launch_bounds__(256) void mm2_kernel(const float* __restrict__ x1A_,
                                                  const float* __restrict__ x1B_,
                                                  const float* __restrict__ x2A_,
                                                  const float* __restrict__ x2B_,
                                                  const float* __restrict__ W,
                                                  float* __restrict__ h1A, float* __restrict__ h1B,
                                                  float* __restrict__ h2A, float* __restrict__ h2B,
                                                  int n) {
    int br = blockIdx.x & 1;
    const float* inA = br ? x2A_ : x1A_;
    const float* inB = br ? x2B_ : x1B_;
    float* hA = br ? h2A : h1A;
    float* hB = br ? h2B : h1B;
    int wid = (blockIdx.x >> 1) * 4 + (threadIdx.x >> 6);
    int lane = threadIdx.x & 63;
    int i0 = wid * 4;
    if (i0 >= n) return;
    float v0[4], v1[4];
#pragma unroll
    for (int r = 0; r < 4; ++r) {
        int i = i0 + r;
        if (i < n) { v0[r] = inA[(size_t)i * 64 + lane]; v1[r] = inB[(size_t)i * 64 + lane]; }
        else { v0[r] = 0.f; v1[r] = 0.f; }
    }
    float acc0[4] = {0.f, 0.f, 0.f, 0.f};
    float acc1[4] = {0.f, 0.f, 0.f, 0.f};
#pragma unroll 4
    for (int k = 0; k < 64; ++k) {
        float w0 = W[k * DF + lane];
        float w1 = W[k * DF + 64 + lane];
#pragma unroll
        for (int r = 0; r < 4; ++r) {
            float a = __shfl(v0[r], k);
            acc0[r] = fmaf(a, w0, acc0[r]);
            acc1[r] = fmaf(a, w1, acc1[r]);
        }
    }
#pragma unroll 4
    for (int k = 0; k < 64; ++k) {
        float w0 = W[(k + 64) * DF + lane];
        float w1 = W[(k + 64) * DF + 64 + lane];
#pragma unroll
        for (int r = 0; r < 4; ++r) {
            float a = __shfl(v1[r], k);
            acc0[r] = fmaf(a, w0, acc0[r]);
            acc1[r] = fmaf(a, w1, acc1[r]);
        }
    }
#pragma unroll
    for (int r = 0; r < 4; ++r) {
        int i = i0 + r;
        if (i < n) { hA[(size_t)i * 64 + lane] = acc0[r]; hB[(size_t)i * 64 + lane] = acc1[r]; }
    }
}

// ---------------- layer-1 dual SpMM, paired across halves (XCD parity), relu ----------------
__global__ __launch_bounds__(256) void spmm_l1_kernel(const float* __restrict__ hA,
                                                      const float* __restrict__ hB,
                                                      const float* __restrict__ wsA,
                                                      const float* __restrict__ wsB,
                                                      const unsigned short* __restrict__ col_s,
                                                      const float* __restrict__ disA,
                                                      const float* __restrict__ disB,
                                                      const int* __restrict__ row_ptr,
                                                      const float* __restrict__ bias,
                                                      float* __restrict__ x1A, float* __restrict__ x1B,
                                                      float* __restrict__ x2A, float* __restrict__ x2B,
                                                      float* __restrict__ sq1pA, float* __restrict__ sq1pB,
                                                      float* __restrict__ sq2pA, float* __restrict__ sq2pB,
                                                      int n) {
    int half = blockIdx.x & 1;
    int wid = (blockIdx.x >> 1) * 4 + (threadIdx.x >> 6);
    int lane = threadIdx.x & 63;
    if (wid >= n) return;
    const float* hH = half ? hB : hA;
    float* x1H = half ? x1B : x1A;
    float* x2H = half ? x2B : x2A;
    float* sq1 = half ? sq1pB : sq1pA;
    float* sq2 = half ? sq2pB : sq2pA;
    const float* biasH = bias + half * 64;
    int sub = lane & 15, g = lane >> 4;
    int s = row_ptr[wid], e = row_ptr[wid + 1];
    float diA = disA[wid], diB = disB[wid];
    float4 aA = make_float4(0.f, 0.f, 0.f, 0.f);
    float4 aB = make_float4(0.f, 0.f, 0.f, 0.f);
    for (int base = s; base < e; base += 64) {
        int m = e - base; if (m > 64) m = 64;
        int cc = 0; float wa = 0.f, wb = 0.f;
        if (lane < m) {
            cc = (int)__builtin_nontemporal_load(col_s + base + lane);
            wa = __builtin_nontemporal_load(wsA + base + lane) * disA[cc];
            wb = __builtin_nontemporal_load(wsB + base + lane) * disB[cc];
        }
#define SPL1_BODY(CHK)                                                       \
        _Pragma("unroll")                                                    \
        for (int it = 0; it < 16; ++it) {                                    \
            int idx = it * 4 + g;                                            \
            int c = __shfl(cc, idx);                                         \
            float ceA = __shfl(wa, idx);                                     \
            float ceB = __shfl(wb, idx);                                     \
            if (CHK) {                                                       \
                float4 gv = ((const float4*)(hH + (size_t)c * 64))[sub];     \
                aA.x = fmaf(ceA, gv.x, aA.x); aA.y = fmaf(ceA, gv.y, aA.y);  \
                aA.z = fmaf(ceA, gv.z, aA.z); aA.w = fmaf(ceA, gv.w, aA.w);  \
                aB.x = fmaf(ceB, gv.x, aB.x); aB.y = fmaf(ceB, gv.y, aB.y);  \
                aB.z = fmaf(ceB, gv.z, aB.z); aB.w = fmaf(ceB, gv.w, aB.w);  \
            }                                                                \
        }
        if (m == 64) { SPL1_BODY(true) } else { SPL1_BODY(idx < m) }
#undef SPL1_BODY
    }
#pragma unroll
    for (int off = 16; off <= 32; off <<= 1) {
        aA.x += __shfl_xor(aA.x, off); aA.y += __shfl_xor(aA.y, off);
        aA.z += __shfl_xor(aA.z, off); aA.w += __shfl_xor(aA.w, off);
        aB.x += __shfl_xor(aB.x, off); aB.y += __shfl_xor(aB.y, off);
        aB.z += __shfl_xor(aB.z, off); aB.w += __shfl_xor(aB.w, off);
    }
    float4 hv = ((const float4*)(hH + (size_t)wid * 64))[sub];
    float4 bb = ((const float4*)biasH)[sub];
    float4 oA, oB;
    oA.x = fmaxf(diA * (aA.x + diA * hv.x) + bb.x, 0.f);
    oA.y = fmaxf(diA * (aA.y + diA * hv.y) + bb.y, 0.f);
    oA.z = fmaxf(diA * (aA.z + diA * hv.z) + bb.z, 0.f);
    oA.w = fmaxf(diA * (aA.w + diA * hv.w) + bb.w, 0.f);
    oB.x = fmaxf(diB * (aB.x + diB * hv.x) + bb.x, 0.f);
    oB.y = fmaxf(diB * (aB.y + diB * hv.y) + bb.y, 0.f);
    oB.z = fmaxf(diB * (aB.z + diB * hv.z) + bb.z, 0.f);
    oB.w = fmaxf(diB * (aB.w + diB * hv.w) + bb.w, 0.f);
    if (g == 0) {
        ((float4*)(x1H + (size_t)wid * 64))[sub] = oA;
        ((float4*)(x2H + (size_t)wid * 64))[sub] = oB;
    }
    float sA = oA.x * oA.x + oA.y * oA.y + oA.z * oA.z + oA.w * oA.w;
    float sB = oB.x * oB.x + oB.y * oB.y + oB.z * oB.z + oB.w * oB.w;
#pragma unroll
    for (int off = 8; off; off >>= 1) {
        sA += __shfl_xor(sA, off);
        sB += __shfl_xor(sB, off);
    }
    if (lane == 0) { sq1[wid] = sA; sq2[wid] = sB; }
}

// ---------------- layer-2 SpMM, paired across branches (XCD parity), one half ----------------
__global__ __launch_bounds__(256) void spmm2_kernel(const float* __restrict__ h0H,
                                                    const float* __restrict__ h1H,
                                                    const float* __restrict__ wsA,
                                                    const float* __restrict__ wsB,
                                                    const unsigned short* __restrict__ col_s,
                                                    const float* __restrict__ disA,
                                                    const float* __restrict__ disB,
                                                    const int* __restrict__ row_ptr,
                                                    const float* __restrict__ biasH,
                                                    float* __restrict__ out0H,
                                                    float* __restrict__ out1H, int n) {
    int br = blockIdx.x & 1;
    int wid = (blockIdx.x >> 1) * 4 + (threadIdx.x >> 6);
    int lane = threadIdx.x & 63;
    if (wid >= n) return;
    const float* hH = br ? h1H : h0H;
    const float* ws = br ? wsB : wsA;
    const float* dis = br ? disB : disA;
    float* outH = br ? out1H : out0H;
    int sub = lane & 15, g = lane >> 4;
    int s = row_ptr[wid], e = row_ptr[wid + 1];
    float di = dis[wid];
    float4 a = make_float4(0.f, 0.f, 0.f, 0.f);
    for (int base = s; base < e; base += 64) {
        int m = e - base; if (m > 64) m = 64;
        int cc = 0; float wv = 0.f;
        if (lane < m) {
            cc = (int)__builtin_nontemporal_load(col_s + base + lane);
            wv = __builtin_nontemporal_load(ws + base + lane) * dis[cc];
        }
#define SP2_BODY(CHK)                                                        \
        _Pragma("unroll")                                                    \
        for (int it = 0; it < 16; ++it) {                                    \
            int idx = it * 4 + g;                                            \
            int c = __shfl(cc, idx);                                         \
            float ce = __shfl(wv, idx);                                      \
            if (CHK) {                                                       \
                float4 gv = ((const float4*)(hH + (size_t)c * 64))[sub];     \
                a.x = fmaf(ce, gv.x, a.x); a.y = fmaf(ce, gv.y, a.y);        \
                a.z = fmaf(ce, gv.z, a.z); a.w = fmaf(ce, gv.w, a.w);        \
            }                                                                \
        }
        if (m == 64) { SP2_BODY(true) } else { SP2_BODY(idx < m) }
#undef SP2_BODY
    }
#pragma unroll
    for (int off = 16; off <= 32; off <<= 1) {
        a.x += __shfl_xor(a.x, off); a.y += __shfl_xor(a.y, off);
        a.z += __shfl_xor(a.z, off); a.w += __shfl_xor(a.w, off);
    }
    if (g == 0) {
        float4 hv = ((const float4*)(hH + (size_t)wid * 64))[sub];
        float4 bb = ((const float4*)biasH)[sub];
        float4 o;
        o.x = di * (a.x + di * hv.x) + bb.x;
        o.y = di * (a.y + di * hv.y) + bb.y;
        o.z = di * (a.z + di * hv.z) + bb.z;
        o.w = di * (a.w + di * hv.w) + bb.w;
        ((float4*)(outH + (size_t)wid * 64))[sub] = o;
    }
}

// ---------------- semantic attention fusion ----------------
__global__ __launch_bounds__(256) void attn_kernel(const float* __restrict__ x1A,
                                                   const float* __restrict__ x1B,
                                                   const float* __restrict__ x2A,
                                                   const float* __restrict__ x2B,
                                                   const float* __restrict__ A1,
                                                   const float* __restrict__ ab1,
                                                   const float* __restrict__ A2,
                                                   float* __restrict__ out, int n) {
    __shared__ float sA1[DF * HATT];
    __shared__ float sA2[HATT];
    __shared__ float sab[HATT];
    int tid = threadIdx.x;
    for (int i = tid; i < DF * HATT; i += 256) sA1[i] = A1[i];
    if (tid < HATT) { sA2[tid] = A2[tid]; sab[tid] = ab1[tid]; }
    __syncthreads();
    int lane = tid & 63;
    int wib = tid >> 6;
    int wid = blockIdx.x * 4 + wib;
    int nw = gridDim.x * 4;
    for (int i = wid; i < n; i += nw) {
        float u0 = x1A[(size_t)i * 64 + lane], u1 = x1B[(size_t)i * 64 + lane];
        float v0 = x2A[(size_t)i * 64 + lane], v1 = x2B[(size_t)i * 64 + lane];
        float acc1 = 0.f, acc2 = 0.f;
#pragma unroll 4
        for (int d = 0; d < 64; ++d) {
            float w = sA1[d * HATT + lane];
            acc1 = fmaf(__shfl(u0, d), w, acc1);
            acc2 = fmaf(__shfl(v0, d), w, acc2);
        }
#pragma unroll 4
        for (int d = 0; d < 64; ++d) {
            float w = sA1[(d + 64) * HATT + lane];
            acc1 = fmaf(__shfl(u1, d), w, acc1);
            acc2 = fmaf(__shfl(v1, d), w, acc2);
        }
        float t1 = tanhf(acc1 + sab[lane]) * sA2[lane];
        float t2 = tanhf(acc2 + sab[lane]) * sA2[lane];
        for (int off = 32; off; off >>= 1) {
            t1 += __shfl_xor(t1, off);
            t2 += __shfl_xor(t2, off);
        }
        float mx = fmaxf(t1, t2);
        float e1 = expf(t1 - mx), e2 = expf(t2 - mx);
        float inv = 1.f / (e1 + e2);
        float be1 = e1 * inv, be2 = e2 * inv;
        out[(size_t)i * DF + lane] = be1 * u0 + be2 * v0;
        out[(size_t)i * DF + 64 + lane] = be1 * u1 + be2 * v1;
    }
}

// ---------------- launch ----------------

extern "C" void kernel_launch(void* const* d_in, const int* in_sizes, int n_in,
                              void* d_out, int out_size, void* d_ws, size_t ws_size,
                              hipStream_t stream) {
    const float* x  = (const float*)d_in[0];
    const int* row  = (const int*)d_in[1];
    const int* col  = (const int*)d_in[2];
    const float* W1 = (const float*)d_in[3];
    const float* b1 = (const float*)d_in[4];
    const float* W2 = (const float*)d_in[5];
    const float* b2 = (const float*)d_in[6];
    const float* A1 = (const float*)d_in[7];
    const float* ab1= (const float*)d_in[8];
    const float* A2 = (const float*)d_in[9];
    const int N = in_sizes[0] / DF;
    const int E = in_sizes[1];
    float* out = (float*)d_out;

    char* p = (char*)d_ws;
    auto alloc_b = [&](size_t bytes) -> char* {
        char* r = p;
        p += (bytes + 255) & ~(size_t)255;
        return r;
    };
    float* xA    = (float*)alloc_b((size_t)N * 64 * 4);
    float* xB    = (float*)alloc_b((size_t)N * 64 * 4);
    float* hA    = (float*)alloc_b((size_t)N * 64 * 4);   // also h1A
    float* hB    = (float*)alloc_b((size_t)N * 64 * 4);   // also h1B
    float* h2A   = (float*)alloc_b((size_t)N * 64 * 4);
    float* h2B   = (float*)alloc_b((size_t)N * 64 * 4);
    float* x1A   = (float*)alloc_b((size_t)N * 64 * 4);
    float* x1B   = (float*)alloc_b((size_t)N * 64 * 4);
    float* x2A   = (float*)alloc_b((size_t)N * 64 * 4);
    float* x2B   = (float*)alloc_b((size_t)N * 64 * 4);
    float* wsA   = (float*)alloc_b((size_t)E * 4);
    float* wsB   = (float*)alloc_b((size_t)E * 4);
    float* dp0   = (float*)alloc_b((size_t)E * 4);
    float* dp1   = (float*)alloc_b((size_t)E * 4);
    float* disA  = (float*)alloc_b((size_t)N * 4);
    float* disB  = (float*)alloc_b((size_t)N * 4);
    float* sqnx  = (float*)alloc_b((size_t)N * 4);
    float* sq1pA = (float*)alloc_b((size_t)N * 4);
    float* sq1pB = (float*)alloc_b((size_t)N * 4);
    float* sq2pA = (float*)alloc_b((size_t)N * 4);
    float* sq2pB = (float*)alloc_b((size_t)N * 4);
    int* cnt2    = (int*)alloc_b((size_t)SL * N * 4);
    int* tot     = (int*)alloc_b((size_t)N * 4);
    int* rowptr  = (int*)alloc_b((size_t)(N + 1) * 4);
    unsigned short* col_s = (unsigned short*)alloc_b((size_t)E * 2);
    (void)ws_size; (void)n_in; (void)out_size;

    const int nodeBlocks  = divup(N * 64, 256);   // 2500: wave per node
    const int pairBlocks  = 2 * nodeBlocks;       // 5000: paired (XCD parity)
    const int mmBlocks    = divup(divup(N, 4), 4);
    const int mm2Blocks   = 2 * mmBlocks;
    const int ranges = divup(N, RPB);
    const int rpb    = divup(N, ranges);
    int es = divup(E, SL); es = (es + 3) & ~3;
    const int prepBlocks = ranges * SL;

    // graph prep
    hist2_kernel<<<prepBlocks, 256, 0, stream>>>(row, cnt2, E, N, ranges, rpb, es);
    split_x_kernel<<<nodeBlocks, 256, 0, stream>>>(x, xA, xB, sqnx, N);
    scanRT_kernel<<<divup(N, 64), 256, 0, stream>>>(cnt2, tot, N);
    scanT_kernel<<<1, 1024, 0, stream>>>(tot, rowptr, N);
    scatter2_kernel<<<prepBlocks, 256, 0, stream>>>(row, col, cnt2, rowptr, col_s, E, N, ranges, rpb, es);

    // shared layer-1 transform
    mm_kernel<<<mmBlocks, 256, 0, stream>>>(x, x + 64, DF, W1, hA, hB, N);

    // layer-1 edge weights (both metrics) + fused degrees
    edgewA_kernel<<<nodeBlocks, 256, 0, stream>>>(xA, col_s, rowptr, dp0, N);
    edgewB1_kernel<<<nodeBlocks, 256, 0, stream>>>(xB, sqnx, col_s, rowptr, dp0,
                                                   wsA, wsB, disA, disB, N);

    // layer-1 dual SpMM, both halves in one launch (XCD parity on hA/hB)
    spmm_l1_kernel<<<pairBlocks, 256, 0, stream>>>(hA, hB, wsA, wsB, col_s, disA, disB,
                                                   rowptr, b1, x1A, x1B, x2A, x2B,
                                                   sq1pA, sq1pB, sq2pA, sq2pB, N);

    // layer-2 edge weights, both branches paired (XCD parity on x1/x2 tables)
    edgewA2_kernel<<<pairBlocks, 256, 0, stream>>>(x1A, x2A, col_s, rowptr, dp0, dp1, N);
    edgewB2_kernel<<<pairBlocks, 256, 0, stream>>>(x1B, x2B, sq1pA, sq1pB, sq2pA, sq2pB,
                                                   col_s, rowptr, dp0, dp1,
                                                   wsA, wsB, disA, disB, N);

    // layer-2 transforms, both branches paired
    mm2_kernel<<<mm2Blocks, 256, 0, stream>>>(x1A, x1B, x2A, x2B, W2, hA, hB, h2A, h2B, N);

    // layer-2 SpMM: two launches (half A then half B), branches paired in each
    spmm2_kernel<<<pairBlocks, 256, 0, stream>>>(hA, h2A, wsA, wsB, col_s, disA, disB,
                                                 rowptr, b2, x1A, x2A, N);
    spmm2_kernel<<<pairBlocks, 256, 0, stream>>>(hB, h2B, wsA, wsB, col_s, disA, disB,
                                                 rowptr, b2 + 64, x1B, x2B, N);

    // semantic attention fusion -> out
    attn_kernel<<<divup(N, 4), 256, 0, stream>>>(x1A, x1B, x2A, x2B, A1, ab1, A2, out, N);
}

// Round 9
// 397.609 us; speedup vs baseline: 1.6906x; 1.0227x over previous
//
#include <hip/hip_runtime.h>
#include <cstdint>
#include <cstddef>

#define DF 128      // feature dim
#define HATT 64     // attention hidden dim
#define SL 64       // edge slices for graph prep
#define RPB 1280    // max rows per range-block (LDS counters)

static inline int divup(int a, int b) { return (a + b - 1) / b; }

typedef int vint4 __attribute__((ext_vector_type(4)));   // nontemporal-compatible

// ---------------- graph prep: 2-level (row-range x edge-slice) ----------------
__global__ __launch_bounds__(256) void hist2_kernel(const int* __restrict__ row,
                                                    int* __restrict__ cnt2,
                                                    int E, int n, int ranges, int rpb, int es) {
    int rb = blockIdx.x % ranges;
    int s  = blockIdx.x / ranges;
    int lo = rb * rpb, hi = min(lo + rpb, n);
    int rows = hi - lo;
    __shared__ int lc[RPB];
    for (int j = threadIdx.x; j < rows; j += 256) lc[j] = 0;
    __syncthreads();
    int i0 = s * es, i1 = min(i0 + es, E);
    const vint4* rv = (const vint4*)row;
    for (int j = i0 / 4 + threadIdx.x; j < i1 / 4; j += 256) {
        vint4 r4 = __builtin_nontemporal_load(rv + j);
        if (r4.x >= lo && r4.x < hi) atomicAdd(&lc[r4.x - lo], 1);
        if (r4.y >= lo && r4.y < hi) atomicAdd(&lc[r4.y - lo], 1);
        if (r4.z >= lo && r4.z < hi) atomicAdd(&lc[r4.z - lo], 1);
        if (r4.w >= lo && r4.w < hi) atomicAdd(&lc[r4.w - lo], 1);
    }
    __syncthreads();
    for (int j = threadIdx.x; j < rows; j += 256) cnt2[(size_t)s * n + lo + j] = lc[j];
}

__global__ __launch_bounds__(256) void scanRT_kernel(int* __restrict__ cnt2,
                                                     int* __restrict__ tot, int n) {
    __shared__ int tile[SL][65];
    int r0 = blockIdx.x * 64;
    int w = threadIdx.x >> 6;
    int lane = threadIdx.x & 63;
    int rows = min(64, n - r0);
    for (int s = w; s < SL; s += 4) {
        int v = (lane < rows) ? cnt2[(size_t)s * n + r0 + lane] : 0;
        tile[s][lane] = v;
    }
    __syncthreads();
    int t = threadIdx.x;
    if (t < rows) {
        int run = 0;
#pragma unroll
        for (int s = 0; s < SL; ++s) {
            int v = tile[s][t];
            tile[s][t] = run;
            run += v;
        }
        tot[r0 + t] = run;
    }
    __syncthreads();
    for (int s = w; s < SL; s += 4) {
        if (lane < rows) cnt2[(size_t)s * n + r0 + lane] = tile[s][lane];
    }
}

__global__ __launch_bounds__(1024) void scanT_kernel(const int* __restrict__ tot,
                                                     int* __restrict__ row_ptr, int n) {
    __shared__ int sums[1024];
    int t = threadIdx.x;
    int chunk = (n + 1023) >> 10;
    int start = t * chunk, end = min(start + chunk, n);
    int s = 0;
    for (int r = start; r < end; ++r) s += tot[r];
    sums[t] = s;
    __syncthreads();
    for (int off = 1; off < 1024; off <<= 1) {
        int v = (t >= off) ? sums[t - off] : 0;
        __syncthreads();
        sums[t] += v;
        __syncthreads();
    }
    int run = sums[t] - s;
    for (int r = start; r < end; ++r) {
        row_ptr[r] = run;
        run += tot[r];
    }
    if (t == 1023) row_ptr[n] = sums[1023];
}

__global__ __launch_bounds__(256) void scatter2_kernel(const int* __restrict__ row,
                                                       const int* __restrict__ col,
                                                       const int* __restrict__ cnt2,
                                                       const int* __restrict__ row_ptr,
                                                       unsigned short* __restrict__ col_s,
                                                       int E, int n, int ranges, int rpb, int es) {
    int rb = blockIdx.x % ranges;
    int s  = blockIdx.x / ranges;
    int lo = rb * rpb, hi = min(lo + rpb, n);
    int rows = hi - lo;
    __shared__ int cur[RPB];
    for (int j = threadIdx.x; j < rows; j += 256)
        cur[j] = cnt2[(size_t)s * n + lo + j] + row_ptr[lo + j];
    __syncthreads();
    int i0 = s * es, i1 = min(i0 + es, E);
    const vint4* rv = (const vint4*)row;
    const vint4* cv = (const vint4*)col;
    for (int j = i0 / 4 + threadIdx.x; j < i1 / 4; j += 256) {
        vint4 r4 = __builtin_nontemporal_load(rv + j);
        bool b0 = (r4.x >= lo && r4.x < hi);
        bool b1 = (r4.y >= lo && r4.y < hi);
        bool b2 = (r4.z >= lo && r4.z < hi);
        bool b3 = (r4.w >= lo && r4.w < hi);
        if (b0 | b1 | b2 | b3) {
            vint4 c4 = __builtin_nontemporal_load(cv + j);
            if (b0) { int p = atomicAdd(&cur[r4.x - lo], 1); col_s[p] = (unsigned short)c4.x; }
            if (b1) { int p = atomicAdd(&cur[r4.y - lo], 1); col_s[p] = (unsigned short)c4.y; }
            if (b2) { int p = atomicAdd(&cur[r4.z - lo], 1); col_s[p] = (unsigned short)c4.z; }
            if (b3) { int p = atomicAdd(&cur[r4.w - lo], 1); col_s[p] = (unsigned short)c4.w; }
        }
    }
}

// ---------------- split x + squared norms ----------------
__global__ __launch_bounds__(256) void split_x_kernel(const float* __restrict__ x,
                                                      float* __restrict__ xA,
                                                      float* __restrict__ xB,
                                                      float* __restrict__ sqn, int n) {
    int wid = (blockIdx.x * blockDim.x + threadIdx.x) >> 6;
    int lane = threadIdx.x & 63;
    if (wid >= n) return;
    float v0 = x[(size_t)wid * DF + lane];
    float v1 = x[(size_t)wid * DF + 64 + lane];
    xA[(size_t)wid * 64 + lane] = v0;
    xB[(size_t)wid * 64 + lane] = v1;
    float s = v0 * v0 + v1 * v1;
    for (int off = 32; off; off >>= 1) s += __shfl_xor(s, off);
    if (lane == 0) sqn[wid] = s;
}

// ---------------- edge weights: contiguous-16 mapping, coalesced writes ----------------
// group g handles edges base + g*16 + it; lane g*16+it keeps its edge's value.

// layer-1 pass A on xA -> dpart
__global__ __launch_bounds__(256) void edgewA_kernel(const float* __restrict__ tA,
                                                     const unsigned short* __restrict__ col_s,
                                                     const int* __restrict__ row_ptr,
                                                     float* __restrict__ dpart, int n) {
    int wid = (blockIdx.x * blockDim.x + threadIdx.x) >> 6;
    int lane = threadIdx.x & 63;
    if (wid >= n) return;
    int sub = lane & 15, g = lane >> 4;
    int s = row_ptr[wid], e = row_ptr[wid + 1];
    float4 a = ((const float4*)(tA + (size_t)wid * 64))[sub];
    for (int base = s; base < e; base += 64) {
        int m = e - base; if (m > 64) m = 64;
        int cc = 0;
        if (lane < m) cc = (int)col_s[base + lane];
        float dkeep = 0.f;
#define EWA_BODY(CHK)                                                        \
        _Pragma("unroll")                                                    \
        for (int it = 0; it < 16; ++it) {                                    \
            int idx = g * 16 + it;                                           \
            int c = __shfl(cc, idx);                                         \
            if (CHK) {                                                       \
                float4 b = ((const float4*)(tA + (size_t)c * 64))[sub];      \
                float d = a.x * b.x + a.y * b.y + a.z * b.z + a.w * b.w;     \
                d += __shfl_xor(d, 8); d += __shfl_xor(d, 4);                \
                d += __shfl_xor(d, 2); d += __shfl_xor(d, 1);                \
                if (sub == it) dkeep = d;                                    \
            }                                                                \
        }
        if (m == 64) { EWA_BODY(true) } else { EWA_BODY(idx < m) }
#undef EWA_BODY
        if (lane < m) dpart[base + lane] = dkeep;
    }
}

// layer-1 pass B: both metrics, fused degrees, coalesced weight writes
__global__ __launch_bounds__(256) void edgewB1_kernel(const float* __restrict__ tB,
                                                      const float* __restrict__ sqn,
                                                      const unsigned short* __restrict__ col_s,
                                                      const int* __restrict__ row_ptr,
                                                      const float* __restrict__ dpart,
                                                      float* __restrict__ wA,
                                                      float* __restrict__ wB,
                                                      float* __restrict__ disA,
                                                      float* __restrict__ disB, int n) {
    int wid = (blockIdx.x * blockDim.x + threadIdx.x) >> 6;
    int lane = threadIdx.x & 63;
    if (wid >= n) return;
    int sub = lane & 15, g = lane >> 4;
    int s = row_ptr[wid], e = row_ptr[wid + 1];
    float4 a = ((const float4*)(tB + (size_t)wid * 64))[sub];
    float na = sqn[wid];
    float accA = 0.f, accB = 0.f;
    for (int base = s; base < e; base += 64) {
        int m = e - base; if (m > 64) m = 64;
        int cc = 0; float dp = 0.f;
        if (lane < m) {
            cc = (int)col_s[base + lane];
            dp = dpart[base + lane];
        }
        float cwk = 0.f, ewk = 0.f;
#define EWB1_BODY(CHK)                                                       \
        _Pragma("unroll")                                                    \
        for (int it = 0; it < 16; ++it) {                                    \
            int idx = g * 16 + it;                                           \
            int c = __shfl(cc, idx);                                         \
            float dpe = __shfl(dp, idx);                                     \
            if (CHK) {                                                       \
                float4 b = ((const float4*)(tB + (size_t)c * 64))[sub];      \
                float d = a.x * b.x + a.y * b.y + a.z * b.z + a.w * b.w;     \
                d += __shfl_xor(d, 8); d += __shfl_xor(d, 4);                \
                d += __shfl_xor(d, 2); d += __shfl_xor(d, 1);                \
                if (sub == it) {                                             \
                    d += dpe;                                                \
                    float nb = sqn[c];                                       \
                    cwk = d / fmaxf(sqrtf(na * nb), 1e-8f);                  \
                    ewk = sqrtf(fmaxf(na + nb - 2.f * d, 0.f) + 1e-12f);     \
                }                                                            \
            }                                                                \
        }
        if (m == 64) { EWB1_BODY(true) } else { EWB1_BODY(idx < m) }
#undef EWB1_BODY
        accA += cwk;
        accB += ewk;
        if (lane < m) {
            wA[base + lane] = cwk;
            wB[base + lane] = ewk;
        }
    }
#pragma unroll
    for (int off = 32; off; off >>= 1) {
        accA += __shfl_xor(accA, off);
        accB += __shfl_xor(accB, off);
    }
    if (lane == 0) {
        float dA = 1.f + accA;
        disA[wid] = (dA > 0.f) ? rsqrtf(fmaxf(dA, 1e-12f)) : 0.f;
        float dB = 1.f + accB;
        disB[wid] = (dB > 0.f) ? rsqrtf(fmaxf(dB, 1e-12f)) : 0.f;
    }
}

// layer-2 pass A, paired across branches (XCD parity)
__global__ __launch_bounds__(256) void edgewA2_kernel(const float* __restrict__ t0,
                                                      const float* __restrict__ t1,
                                                      const unsigned short* __restrict__ col_s,
                                                      const int* __restrict__ row_ptr,
                                                      float* __restrict__ dp0,
                                                      float* __restrict__ dp1, int n) {
    int br = blockIdx.x & 1;
    int wid = (blockIdx.x >> 1) * 4 + (threadIdx.x >> 6);
    int lane = threadIdx.x & 63;
    if (wid >= n) return;
    const float* tA = br ? t1 : t0;
    float* dpart = br ? dp1 : dp0;
    int sub = lane & 15, g = lane >> 4;
    int s = row_ptr[wid], e = row_ptr[wid + 1];
    float4 a = ((const float4*)(tA + (size_t)wid * 64))[sub];
    for (int base = s; base < e; base += 64) {
        int m = e - base; if (m > 64) m = 64;
        int cc = 0;
        if (lane < m) cc = (int)col_s[base + lane];
        float dkeep = 0.f;
#define EWA2_BODY(CHK)                                                       \
        _Pragma("unroll")                                                    \
        for (int it = 0; it < 16; ++it) {                                    \
            int idx = g * 16 + it;                                           \
            int c = __shfl(cc, idx);                                         \
            if (CHK) {                                                       \
                float4 b = ((const float4*)(tA + (size_t)c * 64))[sub];      \
                float d = a.x * b.x + a.y * b.y + a.z * b.z + a.w * b.w;     \
                d += __shfl_xor(d, 8); d += __shfl_xor(d, 4);                \
                d += __shfl_xor(d, 2); d += __shfl_xor(d, 1);                \
                if (sub == it) dkeep = d;                                    \
            }                                                                \
        }
        if (m == 64) { EWA2_BODY(true) } else { EWA2_BODY(idx < m) }
#undef EWA2_BODY
        if (lane < m) dpart[base + lane] = dkeep;
    }
}

// layer-2 pass B, paired: br 0 = cosine on x1 -> wsA,disA ; br 1 = euclid on x2 -> wsB,disB
__global__ __launch_bounds__(256) void edgewB2_kernel(const float* __restrict__ t0B,
                                                      const float* __restrict__ t1B,
                                                      const float* __restrict__ sq1pA,
                                                      const float* __restrict__ sq1pB,
                                                      const float* __restrict__ sq2pA,
                                                      const float* __restrict__ sq2pB,
                                                      const unsigned short* __restrict__ col_s,
                                                      const int* __restrict__ row_ptr,
                                                      const float* __restrict__ dp0,
                                                      const float* __restrict__ dp1,
                                                      float* __restrict__ wsA,
                                                      float* __restrict__ wsB,
                                                      float* __restrict__ disA,
                                                      float* __restrict__ disB, int n) {
    int br = blockIdx.x & 1;
    int wid = (blockIdx.x >> 1) * 4 + (threadIdx.x >> 6);
    int lane = threadIdx.x & 63;
    if (wid >= n) return;
    const float* tB = br ? t1B : t0B;
    const float* sqA = br ? sq2pA : sq1pA;
    const float* sqB = br ? sq2pB : sq1pB;
    const float* dpart = br ? dp1 : dp0;
    float* wOut = br ? wsB : wsA;
    float* disOut = br ? disB : disA;
    int sub = lane & 15, g = lane >> 4;
    int s = row_ptr[wid], e = row_ptr[wid + 1];
    float4 a = ((const float4*)(tB + (size_t)wid * 64))[sub];
    float na = sqA[wid] + sqB[wid];
    float acc = 0.f;
    for (int base = s; base < e; base += 64) {
        int m = e - base; if (m > 64) m = 64;
        int cc = 0; float dp = 0.f;
        if (lane < m) {
            cc = (int)col_s[base + lane];
            dp = dpart[base + lane];
        }
        float wk = 0.f;
#define EWB2_BODY(CHK)                                                       \
        _Pragma("unroll")                                                    \
        for (int it = 0; it < 16; ++it) {                                    \
            int idx = g * 16 + it;                                           \
            int c = __shfl(cc, idx);                                         \
            float dpe = __shfl(dp, idx);                                     \
            if (CHK) {                                                       \
                float4 b = ((const float4*)(tB + (size_t)c * 64))[sub];      \
                float d = a.x * b.x + a.y * b.y + a.z * b.z + a.w * b.w;     \
                d += __shfl_xor(d, 8); d += __shfl_xor(d, 4);                \
                d += __shfl_xor(d, 2); d += __shfl_xor(d, 1);                \
                if (sub == it) {                                             \
                    d += dpe;                                                \
                    float nb = sqA[c] + sqB[c];                              \
                    if (br == 0) wk = d / fmaxf(sqrtf(na * nb), 1e-8f);      \
                    else wk = sqrtf(fmaxf(na + nb - 2.f * d, 0.f) + 1e-12f); \
                }                                                            \
            }                                                                \
        }
        if (m == 64) { EWB2_BODY(true) } else { EWB2_BODY(idx < m) }
#undef EWB2_BODY
        acc += wk;
        if (lane < m) wOut[base + lane] = wk;
    }
#pragma unroll
    for (int off = 32; off; off >>= 1) acc += __shfl_xor(acc, off);
    if (lane == 0) {
        float dg = 1.f + acc;
        disOut[wid] = (dg > 0.f) ? rsqrtf(fmaxf(dg, 1e-12f)) : 0.f;
    }
}

// ---------------- dense matmuls ----------------
__global__ __launch_bounds__(256) void mm_kernel(const float* __restrict__ inA,
                                                 const float* __restrict__ inB,
                                                 int strideIn,
                                                 const float* __restrict__ W,
                                                 float* __restrict__ hA,
                                                 float* __restrict__ hB, int n) {
    int wid = (blockIdx.x * blockDim.x + threadIdx.x) >> 6;
    int lane = threadIdx.x & 63;
    int i0 = wid * 4;
    if (i0 >= n) return;
    float v0[4], v1[4];
#pragma unroll
    for (int r = 0; r < 4; ++r) {
        int i = i0 + r;
        if (i < n) { v0[r] = inA[(size_t)i * strideIn + lane]; v1[r] = inB[(size_t)i * strideIn + lane]; }
        else { v0[r] = 0.f; v1[r] = 0.f; }
    }
    float acc0[4] = {0.f, 0.f, 0.f, 0.f};
    float acc1[4] = {0.f, 0.f, 0.f, 0.f};
#pragma unroll 4
    for (int k = 0; k < 64; ++k) {
        float w0 = W[k * DF + lane];
        float w1 = W[k * DF + 64 + lane];
#pragma unroll
        for (int r = 0; r < 4; ++r) {
            float a = __shfl(v0[r], k);
            acc0[r] = fmaf(a, w0, acc0[r]);
            acc1[r] = fmaf(a, w1, acc1[r]);
        }
    }
#pragma unroll 4
    for (int k = 0; k < 64; ++k) {
        float w0 = W[(k + 64) * DF + lane];
        float w1 = W[(k + 64) * DF + 64 + lane];
#pragma unroll
        for (int r = 0; r < 4; ++r) {
            float a = __shfl(v1[r], k);
            acc0[r] = fmaf(a, w0, acc0[r]);
            acc1[r] = fmaf(a, w1, acc1[r]);
        }
    }
#pragma unroll
    for (int r = 0; r < 4; ++r) {
        int i = i0 + r;
        if (i < n) { hA[(size_t)i * 64 + lane] = acc0[r]; hB[(size_t)i * 64 + lane] = acc1[r]; }
    }
}

// paired layer-2 mm: branch parity
__global__ __launch_bounds__(256) void mm2_kernel(const float* __restrict__ x1A_,
                                                  const float* __restrict__ x1B_,
                                                  const float* __restrict__ x2A_,
                                                  const float* __restrict__ x2B_,
                                                  const float* __restrict__ W,
                                                  float* __restrict__ h1A, float* __restrict__ h1B,
                                                  float* __restrict__ h2A, float* __restrict__ h2B,
                                                  int n) {
    int br = blockIdx.x & 1;
    const float* inA = br ? x2A_ : x1A_;
    const float* inB = br ? x2B_ : x1B_;
    float* hA = br ? h2A : h1A;
    float* hB = br ? h2B : h1B;
    int wid = (blockIdx.x >> 1) * 4 + (threadIdx.x >> 6);
    int lane = threadIdx.x & 63;
    int i0 = wid * 4;
    if (i0 >= n) return;
    float v0[4], v1[4];
#pragma unroll
    for (int r = 0; r < 4; ++r) {
        int i = i0 + r;
        if (i < n) { v0[r] = inA[(size_t)i * 64 + lane]; v1[r] = inB[(size_t)i * 64 + lane]; }
        else { v0[r] = 0.f; v1[r] = 0.f; }
    }
    float acc0[4] = {0.f, 0.f, 0.f, 0.f};
    float acc1[4] = {0.f, 0.f, 0.f, 0.f};
#pragma unroll 4
    for (int k = 0; k < 64; ++k) {
        float w0 = W[k * DF + lane];
        float w1 = W[k * DF + 64 + lane];
#pragma unroll
        for (int r = 0; r < 4; ++r) {
            float a = __shfl(v0[r], k);
            acc0[r] = fmaf(a, w0, acc0[r]);
            acc1[r] = fmaf(a, w1, acc1[r]);
        }
    }
#pragma unroll 4
    for (int k = 0; k < 64; ++k) {
        float w0 = W[(k + 64) * DF + lane];
        float w1 = W[(k + 64) * DF + 64 + lane];
#pragma unroll
        for (int r = 0; r < 4; ++r) {
            float a = __shfl(v1[r], k);
            acc0[r] = fmaf(a, w0, acc0[r]);
            acc1[r] = fmaf(a, w1, acc1[r]);
        }
    }
#pragma unroll
    for (int r = 0; r < 4; ++r) {
        int i = i0 + r;
        if (i < n) { hA[(size_t)i * 64 + lane] = acc0[r]; hB[(size_t)i * 64 + lane] = acc1[r]; }
    }
}

// ---------------- layer-1 dual SpMM, paired across halves (XCD parity), relu ----------------
__global__ __launch_bounds__(256) void spmm_l1_kernel(const float* __restrict__ hA,
                                                      const float* __restrict__ hB,
                                                      const float* __restrict__ wsA,
                                                      const float* __restrict__ wsB,
                                                      const unsigned short* __restrict__ col_s,
                                                      const float* __restrict__ disA,
                                                      const float* __restrict__ disB,
                                                      const int* __restrict__ row_ptr,
                                                      const float* __restrict__ bias,
                                                      float* __restrict__ x1A, float* __restrict__ x1B,
                                                      float* __restrict__ x2A, float* __restrict__ x2B,
                                                      float* __restrict__ sq1pA, float* __restrict__ sq1pB,
                                                      float* __restrict__ sq2pA, float* __restrict__ sq2pB,
                                                      int n) {
    int half = blockIdx.x & 1;
    int wid = (blockIdx.x >> 1) * 4 + (threadIdx.x >> 6);
    int lane = threadIdx.x & 63;
    if (wid >= n) return;
    const float* hH = half ? hB : hA;
    float* x1H = half ? x1B : x1A;
    float* x2H = half ? x2B : x2A;
    float* sq1 = half ? sq1pB : sq1pA;
    float* sq2 = half ? sq2pB : sq2pA;
    const float* biasH = bias + half * 64;
    int sub = lane & 15, g = lane >> 4;
    int s = row_ptr[wid], e = row_ptr[wid + 1];
    float diA = disA[wid], diB = disB[wid];
    float4 aA = make_float4(0.f, 0.f, 0.f, 0.f);
    float4 aB = make_float4(0.f, 0.f, 0.f, 0.f);
    for (int base = s; base < e; base += 64) {
        int m = e - base; if (m > 64) m = 64;
        int cc = 0; float wa = 0.f, wb = 0.f;
        if (lane < m) {
            cc = (int)col_s[base + lane];
            wa = wsA[base + lane] * disA[cc];
            wb = wsB[base + lane] * disB[cc];
        }
#define SPL1_BODY(CHK)                                                       \
        _Pragma("unroll")                                                    \
        for (int it = 0; it < 16; ++it) {                                    \
            int idx = it * 4 + g;                                            \
            int c = __shfl(cc, idx);                                         \
            float ceA = __shfl(wa, idx);                                     \
            float ceB = __shfl(wb, idx);                                     \
            if (CHK) {                                                       \
                float4 gv = ((const float4*)(hH + (size_t)c * 64))[sub];     \
                aA.x = fmaf(ceA, gv.x, aA.x); aA.y = fmaf(ceA, gv.y, aA.y);  \
                aA.z = fmaf(ceA, gv.z, aA.z); aA.w = fmaf(ceA, gv.w, aA.w);  \
                aB.x = fmaf(ceB, gv.x, aB.x); aB.y = fmaf(ceB, gv.y, aB.y);  \
                aB.z = fmaf(ceB, gv.z, aB.z); aB.w = fmaf(ceB, gv.w, aB.w);  \
            }                                                                \
        }
        if (m == 64) { SPL1_BODY(true) } else { SPL1_BODY(idx < m) }
#undef SPL1_BODY
    }
#pragma unroll
    for (int off = 16; off <= 32; off <<= 1) {
        aA.x += __shfl_xor(aA.x, off); aA.y += __shfl_xor(aA.y, off);
        aA.z += __shfl_xor(aA.z, off); aA.w += __shfl_xor(aA.w, off);
        aB.x += __shfl_xor(aB.x, off); aB.y += __shfl_xor(aB.y, off);
        aB.z += __shfl_xor(aB.z, off); aB.w += __shfl_xor(aB.w, off);
    }
    float4 hv = ((const float4*)(hH + (size_t)wid * 64))[sub];
    float4 bb = ((const float4*)biasH)[sub];
    float4 oA, oB;
    oA.x = fmaxf(diA * (aA.x + diA * hv.x) + bb.x, 0.f);
    oA.y = fmaxf(diA * (aA.y + diA * hv.y) + bb.y, 0.f);
    oA.z = fmaxf(diA * (aA.z + diA * hv.z) + bb.z, 0.f);
    oA.w = fmaxf(diA * (aA.w + diA * hv.w) + bb.w, 0.f);
    oB.x = fmaxf(diB * (aB.x + diB * hv.x) + bb.x, 0.f);
    oB.y = fmaxf(diB * (aB.y + diB * hv.y) + bb.y, 0.f);
    oB.z = fmaxf(diB * (aB.z + diB * hv.z) + bb.z, 0.f);
    oB.w = fmaxf(diB * (aB.w + diB * hv.w) + bb.w, 0.f);
    if (g == 0) {
        ((float4*)(x1H + (size_t)wid * 64))[sub] = oA;
        ((float4*)(x2H + (size_t)wid * 64))[sub] = oB;
    }
    float sA = oA.x * oA.x + oA.y * oA.y + oA.z * oA.z + oA.w * oA.w;
    float sB = oB.x * oB.x + oB.y * oB.y + oB.z * oB.z + oB.w * oB.w;
#pragma unroll
    for (int off = 8; off; off >>= 1) {
        sA += __shfl_xor(sA, off);
        sB += __shfl_xor(sB, off);
    }
    if (lane == 0) { sq1[wid] = sA; sq2[wid] = sB; }
}

// ---------------- layer-2 SpMM: 4-way parity (branch x half) in one launch ----------------
__global__ __launch_bounds__(256) void spmm2q_kernel(const float* __restrict__ h1A,
                                                     const float* __restrict__ h1B,
                                                     const float* __restrict__ h2A,
                                                     const float* __restrict__ h2B,
                                                     const float* __restrict__ wsA,
                                                     const float* __restrict__ wsB,
                                                     const unsigned short* __restrict__ col_s,
                                                     const float* __restrict__ disA,
                                                     const float* __restrict__ disB,
                                                     const int* __restrict__ row_ptr,
                                                     const float* __restrict__ bias,
                                                     float* __restrict__ x1A, float* __restrict__ x1B,
                                                     float* __restrict__ x2A, float* __restrict__ x2B,
                                                     int n) {
    int sel = blockIdx.x & 3;
    int br = sel & 1;      // 0 = cosine, 1 = euclid
    int half = sel >> 1;   // 0 = A, 1 = B
    const float* hH = br ? (half ? h2B : h2A) : (half ? h1B : h1A);
    const float* ws = br ? wsB : wsA;
    const float* dis = br ? disB : disA;
    float* outH = br ? (half ? x2B : x2A) : (half ? x1B : x1A);
    const float* biasH = bias + half * 64;
    int wid = (blockIdx.x >> 2) * 4 + (threadIdx.x >> 6);
    int lane = threadIdx.x & 63;
    if (wid >= n) return;
    int sub = lane & 15, g = lane >> 4;
    int s = row_ptr[wid], e = row_ptr[wid + 1];
    float di = dis[wid];
    float4 a = make_float4(0.f, 0.f, 0.f, 0.f);
    for (int base = s; base < e; base += 64) {
        int m = e - base; if (m > 64) m = 64;
        int cc = 0; float wv = 0.f;
        if (lane < m) {
            cc = (int)col_s[base + lane];
            wv = ws[base + lane] * dis[cc];
        }
#define SP2_BODY(CHK)                                                        \
        _Pragma("unroll")                                                    \
        for (int it = 0; it < 16; ++it) {                                    \
            int idx = it * 4 + g;                                            \
            int c = __shfl(cc, idx);                                         \
            float ce = __shfl(wv, idx);                                      \
            if (CHK) {                                                       \
                float4 gv = ((const float4*)(hH + (size_t)c * 64))[sub];     \
                a.x = fmaf(ce, gv.x, a.x); a.y = fmaf(ce, gv.y, a.y);        \
                a.z = fmaf(ce, gv.z, a.z); a.w = fmaf(ce, gv.w, a.w);        \
            }                                                                \
        }
        if (m == 64) { SP2_BODY(true) } else { SP2_BODY(idx < m) }
#undef SP2_BODY
    }
#pragma unroll
    for (int off = 16; off <= 32; off <<= 1) {
        a.x += __shfl_xor(a.x, off); a.y += __shfl_xor(a.y, off);
        a.z += __shfl_xor(a.z, off); a.w += __shfl_xor(a.w, off);
    }
    if (g == 0) {
        float4 hv = ((const float4*)(hH + (size_t)wid * 64))[sub];
        float4 bb = ((const float4*)biasH)[sub];
        float4 o;
        o.x = di * (a.x + di * hv.x) + bb.x;
        o.y = di * (a.y + di * hv.y) + bb.y;
        o.z = di * (a.z + di * hv.z) + bb.z;
        o.w = di * (a.w + di * hv.w) + bb.w;
        ((float4*)(outH + (size_t)wid * 64))[sub] = o;
    }
}

// ---------------- semantic attention fusion ----------------
__global__ __launch_bounds__(256) void attn_kernel(const float* __restrict__ x1A,
                                                   const float* __restrict__ x1B,
                                                   const float* __restrict__ x2A,
                                                   const float* __restrict__ x2B,
                                                   const float* __restrict__ A1,
                                                   const float* __restrict__ ab1,
                                                   const float* __restrict__ A2,
                                                   float* __restrict__ out, int n) {
    __shared__ float sA1[DF * HATT];
    __shared__ float sA2[HATT];
    __shared__ float sab[HATT];
    int tid = threadIdx.x;
    for (int i = tid; i < DF * HATT; i += 256) sA1[i] = A1[i];
    if (tid < HATT) { sA2[tid] = A2[tid]; sab[tid] = ab1[tid]; }
    __syncthreads();
    int lane = tid & 63;
    int wib = tid >> 6;
    int wid = blockIdx.x * 4 + wib;
    int nw = gridDim.x * 4;
    for (int i = wid; i < n; i += nw) {
        float u0 = x1A[(size_t)i * 64 + lane], u1 = x1B[(size_t)i * 64 + lane];
        float v0 = x2A[(size_t)i * 64 + lane], v1 = x2B[(size_t)i * 64 + lane];
        float acc1 = 0.f, acc2 = 0.f;
#pragma unroll 4
        for (int d = 0; d < 64; ++d) {
            float w = sA1[d * HATT + lane];
            acc1 = fmaf(__shfl(u0, d), w, acc1);
            acc2 = fmaf(__shfl(v0, d), w, acc2);
        }
#pragma unroll 4
        for (int d = 0; d < 64; ++d) {
            float w = sA1[(d + 64) * HATT + lane];
            acc1 = fmaf(__shfl(u1, d), w, acc1);
            acc2 = fmaf(__shfl(v1, d), w, acc2);
        }
        float t1 = tanhf(acc1 + sab[lane]) * sA2[lane];
        float t2 = tanhf(acc2 + sab[lane]) * sA2[lane];
        for (int off = 32; off; off >>= 1) {
            t1 += __shfl_xor(t1, off);
            t2 += __shfl_xor(t2, off);
        }
        float mx = fmaxf(t1, t2);
        float e1 = expf(t1 - mx), e2 = expf(t2 - mx);
        float inv = 1.f / (e1 + e2);
        float be1 = e1 * inv, be2 = e2 * inv;
        out[(size_t)i * DF + lane] = be1 * u0 + be2 * v0;
        out[(size_t)i * DF + 64 + lane] = be1 * u1 + be2 * v1;
    }
}

// ---------------- launch ----------------

extern "C" void kernel_launch(void* const* d_in, const int* in_sizes, int n_in,
                              void* d_out, int out_size, void* d_ws, size_t ws_size,
                              hipStream_t stream) {
    const float* x  = (const float*)d_in[0];
    const int* row  = (const int*)d_in[1];
    const int* col  = (const int*)d_in[2];
    const float* W1 = (const float*)d_in[3];
    const float* b1 = (const float*)d_in[4];
    const float* W2 = (const float*)d_in[5];
    const float* b2 = (const float*)d_in[6];
    const float* A1 = (const float*)d_in[7];
    const float* ab1= (const float*)d_in[8];
    const float* A2 = (const float*)d_in[9];
    const int N = in_sizes[0] / DF;
    const int E = in_sizes[1];
    float* out = (float*)d_out;

    char* p = (char*)d_ws;
    auto alloc_b = [&](size_t bytes) -> char* {
        char* r = p;
        p += (bytes + 255) & ~(size_t)255;
        return r;
    };
    float* xA    = (float*)alloc_b((size_t)N * 64 * 4);
    float* xB    = (float*)alloc_b((size_t)N * 64 * 4);
    float* hA    = (float*)alloc_b((size_t)N * 64 * 4);   // also h1A
    float* hB    = (float*)alloc_b((size_t)N * 64 * 4);   // also h1B
    float* h2A   = (float*)alloc_b((size_t)N * 64 * 4);
    float* h2B   = (float*)alloc_b((size_t)N * 64 * 4);
    float* x1A   = (float*)alloc_b((size_t)N * 64 * 4);
    float* x1B   = (float*)alloc_b((size_t)N * 64 * 4);
    float* x2A   = (float*)alloc_b((size_t)N * 64 * 4);
    float* x2B   = (float*)alloc_b((size_t)N * 64 * 4);
    float* wsA   = (float*)alloc_b((size_t)E * 4);
    float* wsB   = (float*)alloc_b((size_t)E * 4);
    float* dp0   = (float*)alloc_b((size_t)E * 4);
    float* dp1   = (float*)alloc_b((size_t)E * 4);
    float* disA  = (float*)alloc_b((size_t)N * 4);
    float* disB  = (float*)alloc_b((size_t)N * 4);
    float* sqnx  = (float*)alloc_b((size_t)N * 4);
    float* sq1pA = (float*)alloc_b((size_t)N * 4);
    float* sq1pB = (float*)alloc_b((size_t)N * 4);
    float* sq2pA = (float*)alloc_b((size_t)N * 4);
    float* sq2pB = (float*)alloc_b((size_t)N * 4);
    int* cnt2    = (int*)alloc_b((size_t)SL * N * 4);
    int* tot     = (int*)alloc_b((size_t)N * 4);
    int* rowptr  = (int*)alloc_b((size_t)(N + 1) * 4);
    unsigned short* col_s = (unsigned short*)alloc_b((size_t)E * 2);
    (void)ws_size; (void)n_in; (void)out_size;

    const int nodeBlocks  = divup(N * 64, 256);   // 2500
    const int pairBlocks  = 2 * nodeBlocks;       // 5000
    const int quadBlocks  = 4 * nodeBlocks;       // 10000
    const int mmBlocks    = divup(divup(N, 4), 4);
    const int mm2Blocks   = 2 * mmBlocks;
    const int ranges = divup(N, RPB);
    const int rpb    = divup(N, ranges);
    int es = divup(E, SL); es = (es + 3) & ~3;
    const int prepBlocks = ranges * SL;

    // graph prep
    hist2_kernel<<<prepBlocks, 256, 0, stream>>>(row, cnt2, E, N, ranges, rpb, es);
    split_x_kernel<<<nodeBlocks, 256, 0, stream>>>(x, xA, xB, sqnx, N);
    scanRT_kernel<<<divup(N, 64), 256, 0, stream>>>(cnt2, tot, N);
    scanT_kernel<<<1, 1024, 0, stream>>>(tot, rowptr, N);
    scatter2_kernel<<<prepBlocks, 256, 0, stream>>>(row, col, cnt2, rowptr, col_s, E, N, ranges, rpb, es);

    // shared layer-1 transform
    mm_kernel<<<mmBlocks, 256, 0, stream>>>(x, x + 64, DF, W1, hA, hB, N);

    // layer-1 edge weights (both metrics) + fused degrees
    edgewA_kernel<<<nodeBlocks, 256, 0, stream>>>(xA, col_s, rowptr, dp0, N);
    edgewB1_kernel<<<nodeBlocks, 256, 0, stream>>>(xB, sqnx, col_s, rowptr, dp0,
                                                   wsA, wsB, disA, disB, N);

    // layer-1 dual SpMM, both halves in one launch
    spmm_l1_kernel<<<pairBlocks, 256, 0, stream>>>(hA, hB, wsA, wsB, col_s, disA, disB,
                                                   rowptr, b1, x1A, x1B, x2A, x2B,
                                                   sq1pA, sq1pB, sq2pA, sq2pB, N);

    // layer-2 edge weights, both branches paired
    edgewA2_kernel<<<pairBlocks, 256, 0, stream>>>(x1A, x2A, col_s, rowptr, dp0, dp1, N);
    edgewB2_kernel<<<pairBlocks, 256, 0, stream>>>(x1B, x2B, sq1pA, sq1pB, sq2pA, sq2pB,
                                                   col_s, rowptr, dp0, dp1,
                                                   wsA, wsB, disA, disB, N);

    // layer-2 transforms, both branches paired
    mm2_kernel<<<mm2Blocks, 256, 0, stream>>>(x1A, x1B, x2A, x2B, W2, hA, hB, h2A, h2B, N);

    // layer-2 SpMM: single 4-way launch (branch x half)
    spmm2q_kernel<<<quadBlocks, 256, 0, stream>>>(hA, hB, h2A, h2B, wsA, wsB, col_s,
                                                  disA, disB, rowptr, b2,
                                                  x1A, x1B, x2A, x2B, N);

    // semantic attention fusion -> out
    attn_kernel<<<divup(N, 4), 256, 0, stream>>>(x1A, x1B, x2A, x2B, A1, ab1, A2, out, N);
}

// Round 10
// 358.084 us; speedup vs baseline: 1.8772x; 1.1104x over previous
//
#include <hip/hip_runtime.h>
#include <cstdint>
#include <cstddef>

#define DF 128      // feature dim
#define HATT 64     // attention hidden dim
#define SL 64       // edge slices for graph prep
#define RPB 1280    // max rows per range-block (LDS counters)

static inline int divup(int a, int b) { return (a + b - 1) / b; }

typedef int vint4 __attribute__((ext_vector_type(4)));   // nontemporal-compatible

// ---------------- graph prep: 2-level (row-range x edge-slice) ----------------
__global__ __launch_bounds__(256) void hist2_kernel(const int* __restrict__ row,
                                                    int* __restrict__ cnt2,
                                                    int E, int n, int ranges, int rpb, int es) {
    int rb = blockIdx.x % ranges;
    int s  = blockIdx.x / ranges;
    int lo = rb * rpb, hi = min(lo + rpb, n);
    int rows = hi - lo;
    __shared__ int lc[RPB];
    for (int j = threadIdx.x; j < rows; j += 256) lc[j] = 0;
    __syncthreads();
    int i0 = s * es, i1 = min(i0 + es, E);
    const vint4* rv = (const vint4*)row;
    for (int j = i0 / 4 + threadIdx.x; j < i1 / 4; j += 256) {
        vint4 r4 = __builtin_nontemporal_load(rv + j);
        if (r4.x >= lo && r4.x < hi) atomicAdd(&lc[r4.x - lo], 1);
        if (r4.y >= lo && r4.y < hi) atomicAdd(&lc[r4.y - lo], 1);
        if (r4.z >= lo && r4.z < hi) atomicAdd(&lc[r4.z - lo], 1);
        if (r4.w >= lo && r4.w < hi) atomicAdd(&lc[r4.w - lo], 1);
    }
    __syncthreads();
    for (int j = threadIdx.x; j < rows; j += 256) cnt2[(size_t)s * n + lo + j] = lc[j];
}

__global__ __launch_bounds__(256) void scanRT_kernel(int* __restrict__ cnt2,
                                                     int* __restrict__ tot, int n) {
    __shared__ int tile[SL][65];
    int r0 = blockIdx.x * 64;
    int w = threadIdx.x >> 6;
    int lane = threadIdx.x & 63;
    int rows = min(64, n - r0);
    for (int s = w; s < SL; s += 4) {
        int v = (lane < rows) ? cnt2[(size_t)s * n + r0 + lane] : 0;
        tile[s][lane] = v;
    }
    __syncthreads();
    int t = threadIdx.x;
    if (t < rows) {
        int run = 0;
#pragma unroll
        for (int s = 0; s < SL; ++s) {
            int v = tile[s][t];
            tile[s][t] = run;
            run += v;
        }
        tot[r0 + t] = run;
    }
    __syncthreads();
    for (int s = w; s < SL; s += 4) {
        if (lane < rows) cnt2[(size_t)s * n + r0 + lane] = tile[s][lane];
    }
}

__global__ __launch_bounds__(1024) void scanT_kernel(const int* __restrict__ tot,
                                                     int* __restrict__ row_ptr, int n) {
    __shared__ int sums[1024];
    int t = threadIdx.x;
    int chunk = (n + 1023) >> 10;
    int start = t * chunk, end = min(start + chunk, n);
    int s = 0;
    for (int r = start; r < end; ++r) s += tot[r];
    sums[t] = s;
    __syncthreads();
    for (int off = 1; off < 1024; off <<= 1) {
        int v = (t >= off) ? sums[t - off] : 0;
        __syncthreads();
        sums[t] += v;
        __syncthreads();
    }
    int run = sums[t] - s;
    for (int r = start; r < end; ++r) {
        row_ptr[r] = run;
        run += tot[r];
    }
    if (t == 1023) row_ptr[n] = sums[1023];
}

__global__ __launch_bounds__(256) void scatter2_kernel(const int* __restrict__ row,
                                                       const int* __restrict__ col,
                                                       const int* __restrict__ cnt2,
                                                       const int* __restrict__ row_ptr,
                                                       unsigned short* __restrict__ col_s,
                                                       int E, int n, int ranges, int rpb, int es) {
    int rb = blockIdx.x % ranges;
    int s  = blockIdx.x / ranges;
    int lo = rb * rpb, hi = min(lo + rpb, n);
    int rows = hi - lo;
    __shared__ int cur[RPB];
    for (int j = threadIdx.x; j < rows; j += 256)
        cur[j] = cnt2[(size_t)s * n + lo + j] + row_ptr[lo + j];
    __syncthreads();
    int i0 = s * es, i1 = min(i0 + es, E);
    const vint4* rv = (const vint4*)row;
    const vint4* cv = (const vint4*)col;
    for (int j = i0 / 4 + threadIdx.x; j < i1 / 4; j += 256) {
        vint4 r4 = __builtin_nontemporal_load(rv + j);
        bool b0 = (r4.x >= lo && r4.x < hi);
        bool b1 = (r4.y >= lo && r4.y < hi);
        bool b2 = (r4.z >= lo && r4.z < hi);
        bool b3 = (r4.w >= lo && r4.w < hi);
        if (b0 | b1 | b2 | b3) {
            vint4 c4 = __builtin_nontemporal_load(cv + j);
            if (b0) { int p = atomicAdd(&cur[r4.x - lo], 1); col_s[p] = (unsigned short)c4.x; }
            if (b1) { int p = atomicAdd(&cur[r4.y - lo], 1); col_s[p] = (unsigned short)c4.y; }
            if (b2) { int p = atomicAdd(&cur[r4.z - lo], 1); col_s[p] = (unsigned short)c4.z; }
            if (b3) { int p = atomicAdd(&cur[r4.w - lo], 1); col_s[p] = (unsigned short)c4.w; }
        }
    }
}

// ---------------- split x + squared norms ----------------
__global__ __launch_bounds__(256) void split_x_kernel(const float* __restrict__ x,
                                                      float* __restrict__ xA,
                                                      float* __restrict__ xB,
                                                      float* __restrict__ sqn, int n) {
    int wid = (blockIdx.x * blockDim.x + threadIdx.x) >> 6;
    int lane = threadIdx.x & 63;
    if (wid >= n) return;
    float v0 = x[(size_t)wid * DF + lane];
    float v1 = x[(size_t)wid * DF + 64 + lane];
    xA[(size_t)wid * 64 + lane] = v0;
    xB[(size_t)wid * 64 + lane] = v1;
    float s = v0 * v0 + v1 * v1;
    for (int off = 32; off; off >>= 1) s += __shfl_xor(s, off);
    if (lane == 0) sqn[wid] = s;
}

// ---------------- edge weights: branchless cndmask-keep inner loop ----------------
// Contiguous mapping: lane L owns edge base+L. Group g's loop it handles edge g*16+it
// (guard idx<m is group-uniform). Inner loop: ONLY dot+butterfly+select. All per-edge
// math (dpart add, norms, divide/sqrt, store) happens at full 64-lane width after.

// pass A (dot of one feature half) -> dpart
__global__ __launch_bounds__(256) void edgewA_kernel(const float* __restrict__ tA,
                                                     const unsigned short* __restrict__ col_s,
                                                     const int* __restrict__ row_ptr,
                                                     float* __restrict__ dpart, int n) {
    int wid = (blockIdx.x * blockDim.x + threadIdx.x) >> 6;
    int lane = threadIdx.x & 63;
    if (wid >= n) return;
    int sub = lane & 15, g = lane >> 4;
    int s = row_ptr[wid], e = row_ptr[wid + 1];
    float4 a = ((const float4*)(tA + (size_t)wid * 64))[sub];
    for (int base = s; base < e; base += 64) {
        int m = e - base; if (m > 64) m = 64;
        int cc = 0;
        if (lane < m) cc = (int)col_s[base + lane];
        float dkeep = 0.f;
#define EWA_BODY(CHK)                                                        \
        _Pragma("unroll")                                                    \
        for (int it = 0; it < 16; ++it) {                                    \
            int idx = g * 16 + it;                                           \
            int c = __shfl(cc, idx);                                         \
            if (CHK) {                                                       \
                float4 b = ((const float4*)(tA + (size_t)c * 64))[sub];      \
                float d = a.x * b.x + a.y * b.y + a.z * b.z + a.w * b.w;     \
                d += __shfl_xor(d, 8); d += __shfl_xor(d, 4);                \
                d += __shfl_xor(d, 2); d += __shfl_xor(d, 1);                \
                dkeep = (sub == it) ? d : dkeep;                             \
            }                                                                \
        }
        if (m == 64) { EWA_BODY(true) } else { EWA_BODY(idx < m) }
#undef EWA_BODY
        if (lane < m) dpart[base + lane] = dkeep;
    }
}

// layer-1 pass B: both metrics, fused degrees; per-edge math at full lane width
__global__ __launch_bounds__(256) void edgewB1_kernel(const float* __restrict__ tB,
                                                      const float* __restrict__ sqn,
                                                      const unsigned short* __restrict__ col_s,
                                                      const int* __restrict__ row_ptr,
                                                      const float* __restrict__ dpart,
                                                      float* __restrict__ wA,
                                                      float* __restrict__ wB,
                                                      float* __restrict__ disA,
                                                      float* __restrict__ disB, int n) {
    int wid = (blockIdx.x * blockDim.x + threadIdx.x) >> 6;
    int lane = threadIdx.x & 63;
    if (wid >= n) return;
    int sub = lane & 15, g = lane >> 4;
    int s = row_ptr[wid], e = row_ptr[wid + 1];
    float4 a = ((const float4*)(tB + (size_t)wid * 64))[sub];
    float na = sqn[wid];
    float accA = 0.f, accB = 0.f;
    for (int base = s; base < e; base += 64) {
        int m = e - base; if (m > 64) m = 64;
        int cc = 0; float dp = 0.f;
        if (lane < m) {
            cc = (int)col_s[base + lane];
            dp = dpart[base + lane];
        }
        float dkeep = 0.f;
#define EWB1_BODY(CHK)                                                       \
        _Pragma("unroll")                                                    \
        for (int it = 0; it < 16; ++it) {                                    \
            int idx = g * 16 + it;                                           \
            int c = __shfl(cc, idx);                                         \
            if (CHK) {                                                       \
                float4 b = ((const float4*)(tB + (size_t)c * 64))[sub];      \
                float d = a.x * b.x + a.y * b.y + a.z * b.z + a.w * b.w;     \
                d += __shfl_xor(d, 8); d += __shfl_xor(d, 4);                \
                d += __shfl_xor(d, 2); d += __shfl_xor(d, 1);                \
                dkeep = (sub == it) ? d : dkeep;                             \
            }                                                                \
        }
        if (m == 64) { EWB1_BODY(true) } else { EWB1_BODY(idx < m) }
#undef EWB1_BODY
        if (lane < m) {
            float d = dkeep + dp;
            float nb = sqn[cc];
            float cw = d / fmaxf(sqrtf(na * nb), 1e-8f);
            float ew = sqrtf(fmaxf(na + nb - 2.f * d, 0.f) + 1e-12f);
            wA[base + lane] = cw;
            wB[base + lane] = ew;
            accA += cw;
            accB += ew;
        }
    }
#pragma unroll
    for (int off = 32; off; off >>= 1) {
        accA += __shfl_xor(accA, off);
        accB += __shfl_xor(accB, off);
    }
    if (lane == 0) {
        float dA = 1.f + accA;
        disA[wid] = (dA > 0.f) ? rsqrtf(fmaxf(dA, 1e-12f)) : 0.f;
        float dB = 1.f + accB;
        disB[wid] = (dB > 0.f) ? rsqrtf(fmaxf(dB, 1e-12f)) : 0.f;
    }
}

// layer-2 pass A, paired across branches (XCD parity)
__global__ __launch_bounds__(256) void edgewA2_kernel(const float* __restrict__ t0,
                                                      const float* __restrict__ t1,
                                                      const unsigned short* __restrict__ col_s,
                                                      const int* __restrict__ row_ptr,
                                                      float* __restrict__ dp0,
                                                      float* __restrict__ dp1, int n) {
    int br = blockIdx.x & 1;
    int wid = (blockIdx.x >> 1) * 4 + (threadIdx.x >> 6);
    int lane = threadIdx.x & 63;
    if (wid >= n) return;
    const float* tA = br ? t1 : t0;
    float* dpart = br ? dp1 : dp0;
    int sub = lane & 15, g = lane >> 4;
    int s = row_ptr[wid], e = row_ptr[wid + 1];
    float4 a = ((const float4*)(tA + (size_t)wid * 64))[sub];
    for (int base = s; base < e; base += 64) {
        int m = e - base; if (m > 64) m = 64;
        int cc = 0;
        if (lane < m) cc = (int)col_s[base + lane];
        float dkeep = 0.f;
#define EWA2_BODY(CHK)                                                       \
        _Pragma("unroll")                                                    \
        for (int it = 0; it < 16; ++it) {                                    \
            int idx = g * 16 + it;                                           \
            int c = __shfl(cc, idx);                                         \
            if (CHK) {                                                       \
                float4 b = ((const float4*)(tA + (size_t)c * 64))[sub];      \
                float d = a.x * b.x + a.y * b.y + a.z * b.z + a.w * b.w;     \
                d += __shfl_xor(d, 8); d += __shfl_xor(d, 4);                \
                d += __shfl_xor(d, 2); d += __shfl_xor(d, 1);                \
                dkeep = (sub == it) ? d : dkeep;                             \
            }                                                                \
        }
        if (m == 64) { EWA2_BODY(true) } else { EWA2_BODY(idx < m) }
#undef EWA2_BODY
        if (lane < m) dpart[base + lane] = dkeep;
    }
}

// layer-2 pass B, paired: br 0 = cosine on x1 -> wsA,disA ; br 1 = euclid on x2 -> wsB,disB
__global__ __launch_bounds__(256) void edgewB2_kernel(const float* __restrict__ t0B,
                                                      const float* __restrict__ t1B,
                                                      const float* __restrict__ sq1pA,
                                                      const float* __restrict__ sq1pB,
                                                      const float* __restrict__ sq2pA,
                                                      const float* __restrict__ sq2pB,
                                                      const unsigned short* __restrict__ col_s,
                                                      const int* __restrict__ row_ptr,
                                                      const float* __restrict__ dp0,
                                                      const float* __restrict__ dp1,
                                                      float* __restrict__ wsA,
                                                      float* __restrict__ wsB,
                                                      float* __restrict__ disA,
                                                      float* __restrict__ disB, int n) {
    int br = blockIdx.x & 1;
    int wid = (blockIdx.x >> 1) * 4 + (threadIdx.x >> 6);
    int lane = threadIdx.x & 63;
    if (wid >= n) return;
    const float* tB = br ? t1B : t0B;
    const float* sqA = br ? sq2pA : sq1pA;
    const float* sqB = br ? sq2pB : sq1pB;
    const float* dpart = br ? dp1 : dp0;
    float* wOut = br ? wsB : wsA;
    float* disOut = br ? disB : disA;
    int sub = lane & 15, g = lane >> 4;
    int s = row_ptr[wid], e = row_ptr[wid + 1];
    float4 a = ((const float4*)(tB + (size_t)wid * 64))[sub];
    float na = sqA[wid] + sqB[wid];
    float acc = 0.f;
    for (int base = s; base < e; base += 64) {
        int m = e - base; if (m > 64) m = 64;
        int cc = 0; float dp = 0.f;
        if (lane < m) {
            cc = (int)col_s[base + lane];
            dp = dpart[base + lane];
        }
        float dkeep = 0.f;
#define EWB2_BODY(CHK)                                                       \
        _Pragma("unroll")                                                    \
        for (int it = 0; it < 16; ++it) {                                    \
            int idx = g * 16 + it;                                           \
            int c = __shfl(cc, idx);                                         \
            if (CHK) {                                                       \
                float4 b = ((const float4*)(tB + (size_t)c * 64))[sub];      \
                float d = a.x * b.x + a.y * b.y + a.z * b.z + a.w * b.w;     \
                d += __shfl_xor(d, 8); d += __shfl_xor(d, 4);                \
                d += __shfl_xor(d, 2); d += __shfl_xor(d, 1);                \
                dkeep = (sub == it) ? d : dkeep;                             \
            }                                                                \
        }
        if (m == 64) { EWB2_BODY(true) } else { EWB2_BODY(idx < m) }
#undef EWB2_BODY
        if (lane < m) {
            float d = dkeep + dp;
            float nb = sqA[cc] + sqB[cc];
            float w;
            if (br == 0) w = d / fmaxf(sqrtf(na * nb), 1e-8f);
            else w = sqrtf(fmaxf(na + nb - 2.f * d, 0.f) + 1e-12f);
            wOut[base + lane] = w;
            acc += w;
        }
    }
#pragma unroll
    for (int off = 32; off; off >>= 1) acc += __shfl_xor(acc, off);
    if (lane == 0) {
        float dg = 1.f + acc;
        disOut[wid] = (dg > 0.f) ? rsqrtf(fmaxf(dg, 1e-12f)) : 0.f;
    }
}

// ---------------- dense matmuls ----------------
__global__ __launch_bounds__(256) void mm_kernel(const float* __restrict__ inA,
                                                 const float* __restrict__ inB,
                                                 int strideIn,
                                                 const float* __restrict__ W,
                                                 float* __restrict__ hA,
                                                 float* __restrict__ hB, int n) {
    int wid = (blockIdx.x * blockDim.x + threadIdx.x) >> 6;
    int lane = threadIdx.x & 63;
    int i0 = wid * 4;
    if (i0 >= n) return;
    float v0[4], v1[4];
#pragma unroll
    for (int r = 0; r < 4; ++r) {
        int i = i0 + r;
        if (i < n) { v0[r] = inA[(size_t)i * strideIn + lane]; v1[r] = inB[(size_t)i * strideIn + lane]; }
        else { v0[r] = 0.f; v1[r] = 0.f; }
    }
    float acc0[4] = {0.f, 0.f, 0.f, 0.f};
    float acc1[4] = {0.f, 0.f, 0.f, 0.f};
#pragma unroll 4
    for (int k = 0; k < 64; ++k) {
        float w0 = W[k * DF + lane];
        float w1 = W[k * DF + 64 + lane];
#pragma unroll
        for (int r = 0; r < 4; ++r) {
            float a = __shfl(v0[r], k);
            acc0[r] = fmaf(a, w0, acc0[r]);
            acc1[r] = fmaf(a, w1, acc1[r]);
        }
    }
#pragma unroll 4
    for (int k = 0; k < 64; ++k) {
        float w0 = W[(k + 64) * DF + lane];
        float w1 = W[(k + 64) * DF + 64 + lane];
#pragma unroll
        for (int r = 0; r < 4; ++r) {
            float a = __shfl(v1[r], k);
            acc0[r] = fmaf(a, w0, acc0[r]);
            acc1[r] = fmaf(a, w1, acc1[r]);
        }
    }
#pragma unroll
    for (int r = 0; r < 4; ++r) {
        int i = i0 + r;
        if (i < n) { hA[(size_t)i * 64 + lane] = acc0[r]; hB[(size_t)i * 64 + lane] = acc1[r]; }
    }
}

// paired layer-2 mm: branch parity
__global__ __launch_bounds__(256) void mm2_kernel(const float* __restrict__ x1A_,
                                                  const float* __restrict__ x1B_,
                                                  const float* __restrict__ x2A_,
                                                  const float* __restrict__ x2B_,
                                                  const float* __restrict__ W,
                                                  float* __restrict__ h1A, float* __restrict__ h1B,
                                                  float* __restrict__ h2A, float* __restrict__ h2B,
                                                  int n) {
    int br = blockIdx.x & 1;
    const float* inA = br ? x2A_ : x1A_;
    const float* inB = br ? x2B_ : x1B_;
    float* hA = br ? h2A : h1A;
    float* hB = br ? h2B : h1B;
    int wid = (blockIdx.x >> 1) * 4 + (threadIdx.x >> 6);
    int lane = threadIdx.x & 63;
    int i0 = wid * 4;
    if (i0 >= n) return;
    float v0[4], v1[4];
#pragma unroll
    for (int r = 0; r < 4; ++r) {
        int i = i0 + r;
        if (i < n) { v0[r] = inA[(size_t)i * 64 + lane]; v1[r] = inB[(size_t)i * 64 + lane]; }
        else { v0[r] = 0.f; v1[r] = 0.f; }
    }
    float acc0[4] = {0.f, 0.f, 0.f, 0.f};
    float acc1[4] = {0.f, 0.f, 0.f, 0.f};
#pragma unroll 4
    for (int k = 0; k < 64; ++k) {
        float w0 = W[k * DF + lane];
        float w1 = W[k * DF + 64 + lane];
#pragma unroll
        for (int r = 0; r < 4; ++r) {
            float a = __shfl(v0[r], k);
            acc0[r] = fmaf(a, w0, acc0[r]);
            acc1[r] = fmaf(a, w1, acc1[r]);
        }
    }
#pragma unroll 4
    for (int k = 0; k < 64; ++k) {
        float w0 = W[(k + 64) * DF + lane];
        float w1 = W[(k + 64) * DF + 64 + lane];
#pragma unroll
        for (int r = 0; r < 4; ++r) {
            float a = __shfl(v1[r], k);
            acc0[r] = fmaf(a, w0, acc0[r]);
            acc1[r] = fmaf(a, w1, acc1[r]);
        }
    }
#pragma unroll
    for (int r = 0; r < 4; ++r) {
        int i = i0 + r;
        if (i < n) { hA[(size_t)i * 64 + lane] = acc0[r]; hB[(size_t)i * 64 + lane] = acc1[r]; }
    }
}

// ---------------- layer-1 dual SpMM, paired across halves (XCD parity), relu ----------------
__global__ __launch_bounds__(256) void spmm_l1_kernel(const float* __restrict__ hA,
                                                      const float* __restrict__ hB,
                                                      const float* __restrict__ wsA,
                                                      const float* __restrict__ wsB,
                                                      const unsigned short* __restrict__ col_s,
                                                      const float* __restrict__ disA,
                                                      const float* __restrict__ disB,
                                                      const int* __restrict__ row_ptr,
                                                      const float* __restrict__ bias,
                                                      float* __restrict__ x1A, float* __restrict__ x1B,
                                                      float* __restrict__ x2A, float* __restrict__ x2B,
                                                      float* __restrict__ sq1pA, float* __restrict__ sq1pB,
                                                      float* __restrict__ sq2pA, float* __restrict__ sq2pB,
                                                      int n) {
    int half = blockIdx.x & 1;
    int wid = (blockIdx.x >> 1) * 4 + (threadIdx.x >> 6);
    int lane = threadIdx.x & 63;
    if (wid >= n) return;
    const float* hH = half ? hB : hA;
    float* x1H = half ? x1B : x1A;
    float* x2H = half ? x2B : x2A;
    float* sq1 = half ? sq1pB : sq1pA;
    float* sq2 = half ? sq2pB : sq2pA;
    const float* biasH = bias + half * 64;
    int sub = lane & 15, g = lane >> 4;
    int s = row_ptr[wid], e = row_ptr[wid + 1];
    float diA = disA[wid], diB = disB[wid];
    float4 aA = make_float4(0.f, 0.f, 0.f, 0.f);
    float4 aB = make_float4(0.f, 0.f, 0.f, 0.f);
    for (int base = s; base < e; base += 64) {
        int m = e - base; if (m > 64) m = 64;
        int cc = 0; float wa = 0.f, wb = 0.f;
        if (lane < m) {
            cc = (int)col_s[base + lane];
            wa = wsA[base + lane] * disA[cc];
            wb = wsB[base + lane] * disB[cc];
        }
#define SPL1_BODY(CHK)                                                       \
        _Pragma("unroll")                                                    \
        for (int it = 0; it < 16; ++it) {                                    \
            int idx = it * 4 + g;                                            \
            int c = __shfl(cc, idx);                                         \
            float ceA = __shfl(wa, idx);                                     \
            float ceB = __shfl(wb, idx);                                     \
            if (CHK) {                                                       \
                float4 gv = ((const float4*)(hH + (size_t)c * 64))[sub];     \
                aA.x = fmaf(ceA, gv.x, aA.x); aA.y = fmaf(ceA, gv.y, aA.y);  \
                aA.z = fmaf(ceA, gv.z, aA.z); aA.w = fmaf(ceA, gv.w, aA.w);  \
                aB.x = fmaf(ceB, gv.x, aB.x); aB.y = fmaf(ceB, gv.y, aB.y);  \
                aB.z = fmaf(ceB, gv.z, aB.z); aB.w = fmaf(ceB, gv.w, aB.w);  \
            }                                                                \
        }
        if (m == 64) { SPL1_BODY(true) } else { SPL1_BODY(idx < m) }
#undef SPL1_BODY
    }
#pragma unroll
    for (int off = 16; off <= 32; off <<= 1) {
        aA.x += __shfl_xor(aA.x, off); aA.y += __shfl_xor(aA.y, off);
        aA.z += __shfl_xor(aA.z, off); aA.w += __shfl_xor(aA.w, off);
        aB.x += __shfl_xor(aB.x, off); aB.y += __shfl_xor(aB.y, off);
        aB.z += __shfl_xor(aB.z, off); aB.w += __shfl_xor(aB.w, off);
    }
    float4 hv = ((const float4*)(hH + (size_t)wid * 64))[sub];
    float4 bb = ((const float4*)biasH)[sub];
    float4 oA, oB;
    oA.x = fmaxf(diA * (aA.x + diA * hv.x) + bb.x, 0.f);
    oA.y = fmaxf(diA * (aA.y + diA * hv.y) + bb.y, 0.f);
    oA.z = fmaxf(diA * (aA.z + diA * hv.z) + bb.z, 0.f);
    oA.w = fmaxf(diA * (aA.w + diA * hv.w) + bb.w, 0.f);
    oB.x = fmaxf(diB * (aB.x + diB * hv.x) + bb.x, 0.f);
    oB.y = fmaxf(diB * (aB.y + diB * hv.y) + bb.y, 0.f);
    oB.z = fmaxf(diB * (aB.z + diB * hv.z) + bb.z, 0.f);
    oB.w = fmaxf(diB * (aB.w + diB * hv.w) + bb.w, 0.f);
    if (g == 0) {
        ((float4*)(x1H + (size_t)wid * 64))[sub] = oA;
        ((float4*)(x2H + (size_t)wid * 64))[sub] = oB;
    }
    float sA = oA.x * oA.x + oA.y * oA.y + oA.z * oA.z + oA.w * oA.w;
    float sB = oB.x * oB.x + oB.y * oB.y + oB.z * oB.z + oB.w * oB.w;
#pragma unroll
    for (int off = 8; off; off >>= 1) {
        sA += __shfl_xor(sA, off);
        sB += __shfl_xor(sB, off);
    }
    if (lane == 0) { sq1[wid] = sA; sq2[wid] = sB; }
}

// ---------------- layer-2 SpMM: 4-way parity (branch x half) in one launch ----------------
__global__ __launch_bounds__(256) void spmm2q_kernel(const float* __restrict__ h1A,
                                                     const float* __restrict__ h1B,
                                                     const float* __restrict__ h2A,
                                                     const float* __restrict__ h2B,
                                                     const float* __restrict__ wsA,
                                                     const float* __restrict__ wsB,
                                                     const unsigned short* __restrict__ col_s,
                                                     const float* __restrict__ disA,
                                                     const float* __restrict__ disB,
                                                     const int* __restrict__ row_ptr,
                                                     const float* __restrict__ bias,
                                                     float* __restrict__ x1A, float* __restrict__ x1B,
                                                     float* __restrict__ x2A, float* __restrict__ x2B,
                                                     int n) {
    int sel = blockIdx.x & 3;
    int br = sel & 1;      // 0 = cosine, 1 = euclid
    int half = sel >> 1;   // 0 = A, 1 = B
    const float* hH = br ? (half ? h2B : h2A) : (half ? h1B : h1A);
    const float* ws = br ? wsB : wsA;
    const float* dis = br ? disB : disA;
    float* outH = br ? (half ? x2B : x2A) : (half ? x1B : x1A);
    const float* biasH = bias + half * 64;
    int wid = (blockIdx.x >> 2) * 4 + (threadIdx.x >> 6);
    int lane = threadIdx.x & 63;
    if (wid >= n) return;
    int sub = lane & 15, g = lane >> 4;
    int s = row_ptr[wid], e = row_ptr[wid + 1];
    float di = dis[wid];
    float4 a = make_float4(0.f, 0.f, 0.f, 0.f);
    for (int base = s; base < e; base += 64) {
        int m = e - base; if (m > 64) m = 64;
        int cc = 0; float wv = 0.f;
        if (lane < m) {
            cc = (int)col_s[base + lane];
            wv = ws[base + lane] * dis[cc];
        }
#define SP2_BODY(CHK)                                                        \
        _Pragma("unroll")                                                    \
        for (int it = 0; it < 16; ++it) {                                    \
            int idx = it * 4 + g;                                            \
            int c = __shfl(cc, idx);                                         \
            float ce = __shfl(wv, idx);                                      \
            if (CHK) {                                                       \
                float4 gv = ((const float4*)(hH + (size_t)c * 64))[sub];     \
                a.x = fmaf(ce, gv.x, a.x); a.y = fmaf(ce, gv.y, a.y);        \
                a.z = fmaf(ce, gv.z, a.z); a.w = fmaf(ce, gv.w, a.w);        \
            }                                                                \
        }
        if (m == 64) { SP2_BODY(true) } else { SP2_BODY(idx < m) }
#undef SP2_BODY
    }
#pragma unroll
    for (int off = 16; off <= 32; off <<= 1) {
        a.x += __shfl_xor(a.x, off); a.y += __shfl_xor(a.y, off);
        a.z += __shfl_xor(a.z, off); a.w += __shfl_xor(a.w, off);
    }
    if (g == 0) {
        float4 hv = ((const float4*)(hH + (size_t)wid * 64))[sub];
        float4 bb = ((const float4*)biasH)[sub];
        float4 o;
        o.x = di * (a.x + di * hv.x) + bb.x;
        o.y = di * (a.y + di * hv.y) + bb.y;
        o.z = di * (a.z + di * hv.z) + bb.z;
        o.w = di * (a.w + di * hv.w) + bb.w;
        ((float4*)(outH + (size_t)wid * 64))[sub] = o;
    }
}

// ---------------- semantic attention fusion ----------------
__global__ __launch_bounds__(256) void attn_kernel(const float* __restrict__ x1A,
                                                   const float* __restrict__ x1B,
                                                   const float* __restrict__ x2A,
                                                   const float* __restrict__ x2B,
                                                   const float* __restrict__ A1,
                                                   const float* __restrict__ ab1,
                                                   const float* __restrict__ A2,
                                                   float* __restrict__ out, int n) {
    __shared__ float sA1[DF * HATT];
    __shared__ float sA2[HATT];
    __shared__ float sab[HATT];
    int tid = threadIdx.x;
    for (int i = tid; i < DF * HATT; i += 256) sA1[i] = A1[i];
    if (tid < HATT) { sA2[tid] = A2[tid]; sab[tid] = ab1[tid]; }
    __syncthreads();
    int lane = tid & 63;
    int wib = tid >> 6;
    int wid = blockIdx.x * 4 + wib;
    int nw = gridDim.x * 4;
    for (int i = wid; i < n; i += nw) {
        float u0 = x1A[(size_t)i * 64 + lane], u1 = x1B[(size_t)i * 64 + lane];
        float v0 = x2A[(size_t)i * 64 + lane], v1 = x2B[(size_t)i * 64 + lane];
        float acc1 = 0.f, acc2 = 0.f;
#pragma unroll 4
        for (int d = 0; d < 64; ++d) {
            float w = sA1[d * HATT + lane];
            acc1 = fmaf(__shfl(u0, d), w, acc1);
            acc2 = fmaf(__shfl(v0, d), w, acc2);
        }
#pragma unroll 4
        for (int d = 0; d < 64; ++d) {
            float w = sA1[(d + 64) * HATT + lane];
            acc1 = fmaf(__shfl(u1, d), w, acc1);
            acc2 = fmaf(__shfl(v1, d), w, acc2);
        }
        float t1 = tanhf(acc1 + sab[lane]) * sA2[lane];
        float t2 = tanhf(acc2 + sab[lane]) * sA2[lane];
        for (int off = 32; off; off >>= 1) {
            t1 += __shfl_xor(t1, off);
            t2 += __shfl_xor(t2, off);
        }
        float mx = fmaxf(t1, t2);
        float e1 = expf(t1 - mx), e2 = expf(t2 - mx);
        float inv = 1.f / (e1 + e2);
        float be1 = e1 * inv, be2 = e2 * inv;
        out[(size_t)i * DF + lane] = be1 * u0 + be2 * v0;
        out[(size_t)i * DF + 64 + lane] = be1 * u1 + be2 * v1;
    }
}

// ---------------- launch ----------------

extern "C" void kernel_launch(void* const* d_in, const int* in_sizes, int n_in,
                              void* d_out, int out_size, void* d_ws, size_t ws_size,
                              hipStream_t stream) {
    const float* x  = (const float*)d_in[0];
    const int* row  = (const int*)d_in[1];
    const int* col  = (const int*)d_in[2];
    const float* W1 = (const float*)d_in[3];
    const float* b1 = (const float*)d_in[4];
    const float* W2 = (const float*)d_in[5];
    const float* b2 = (const float*)d_in[6];
    const float* A1 = (const float*)d_in[7];
    const float* ab1= (const float*)d_in[8];
    const float* A2 = (const float*)d_in[9];
    const int N = in_sizes[0] / DF;
    const int E = in_sizes[1];
    float* out = (float*)d_out;

    char* p = (char*)d_ws;
    auto alloc_b = [&](size_t bytes) -> char* {
        char* r = p;
        p += (bytes + 255) & ~(size_t)255;
        return r;
    };
    float* xA    = (float*)alloc_b((size_t)N * 64 * 4);
    float* xB    = (float*)alloc_b((size_t)N * 64 * 4);
    float* hA    = (float*)alloc_b((size_t)N * 64 * 4);   // also h1A
    float* hB    = (float*)alloc_b((size_t)N * 64 * 4);   // also h1B
    float* h2A   = (float*)alloc_b((size_t)N * 64 * 4);
    float* h2B   = (float*)alloc_b((size_t)N * 64 * 4);
    float* x1A   = (float*)alloc_b((size_t)N * 64 * 4);
    float* x1B   = (float*)alloc_b((size_t)N * 64 * 4);
    float* x2A   = (float*)alloc_b((size_t)N * 64 * 4);
    float* x2B   = (float*)alloc_b((size_t)N * 64 * 4);
    float* wsA   = (float*)alloc_b((size_t)E * 4);
    float* wsB   = (float*)alloc_b((size_t)E * 4);
    float* dp0   = (float*)alloc_b((size_t)E * 4);
    float* dp1   = (float*)alloc_b((size_t)E * 4);
    float* disA  = (float*)alloc_b((size_t)N * 4);
    float* disB  = (float*)alloc_b((size_t)N * 4);
    float* sqnx  = (float*)alloc_b((size_t)N * 4);
    float* sq1pA = (float*)alloc_b((size_t)N * 4);
    float* sq1pB = (float*)alloc_b((size_t)N * 4);
    float* sq2pA = (float*)alloc_b((size_t)N * 4);
    float* sq2pB = (float*)alloc_b((size_t)N * 4);
    int* cnt2    = (int*)alloc_b((size_t)SL * N * 4);
    int* tot     = (int*)alloc_b((size_t)N * 4);
    int* rowptr  = (int*)alloc_b((size_t)(N + 1) * 4);
    unsigned short* col_s = (unsigned short*)alloc_b((size_t)E * 2);
    (void)ws_size; (void)n_in; (void)out_size;

    const int nodeBlocks  = divup(N * 64, 256);   // 2500
    const int pairBlocks  = 2 * nodeBlocks;       // 5000
    const int quadBlocks  = 4 * nodeBlocks;       // 10000
    const int mmBlocks    = divup(divup(N, 4), 4);
    const int mm2Blocks   = 2 * mmBlocks;
    const int ranges = divup(N, RPB);
    const int rpb    = divup(N, ranges);
    int es = divup(E, SL); es = (es + 3) & ~3;
    const int prepBlocks = ranges * SL;

    // graph prep
    hist2_kernel<<<prepBlocks, 256, 0, stream>>>(row, cnt2, E, N, ranges, rpb, es);
    split_x_kernel<<<nodeBlocks, 256, 0, stream>>>(x, xA, xB, sqnx, N);
    scanRT_kernel<<<divup(N, 64), 256, 0, stream>>>(cnt2, tot, N);
    scanT_kernel<<<1, 1024, 0, stream>>>(tot, rowptr, N);
    scatter2_kernel<<<prepBlocks, 256, 0, stream>>>(row, col, cnt2, rowptr, col_s, E, N, ranges, rpb, es);

    // shared layer-1 transform
    mm_kernel<<<mmBlocks, 256, 0, stream>>>(x, x + 64, DF, W1, hA, hB, N);

    // layer-1 edge weights (both metrics) + fused degrees
    edgewA_kernel<<<nodeBlocks, 256, 0, stream>>>(xA, col_s, rowptr, dp0, N);
    edgewB1_kernel<<<nodeBlocks, 256, 0, stream>>>(xB, sqnx, col_s, rowptr, dp0,
                                                   wsA, wsB, disA, disB, N);

    // layer-1 dual SpMM, both halves in one launch
    spmm_l1_kernel<<<pairBlocks, 256, 0, stream>>>(hA, hB, wsA, wsB, col_s, disA, disB,
                                                   rowptr, b1, x1A, x1B, x2A, x2B,
                                                   sq1pA, sq1pB, sq2pA, sq2pB, N);

    // layer-2 edge weights, both branches paired
    edgewA2_kernel<<<pairBlocks, 256, 0, stream>>>(x1A, x2A, col_s, rowptr, dp0, dp1, N);
    edgewB2_kernel<<<pairBlocks, 256, 0, stream>>>(x1B, x2B, sq1pA, sq1pB, sq2pA, sq2pB,
                                                   col_s, rowptr, dp0, dp1,
                                                   wsA, wsB, disA, disB, N);

    // layer-2 transforms, both branches paired
    mm2_kernel<<<mm2Blocks, 256, 0, stream>>>(x1A, x1B, x2A, x2B, W2, hA, hB, h2A, h2B, N);

    // layer-2 SpMM: single 4-way launch (branch x half)
    spmm2q_kernel<<<quadBlocks, 256, 0, stream>>>(hA, hB, h2A, h2B, wsA, wsB, col_s,
                                                  disA, disB, rowptr, b2,
                                                  x1A, x1B, x2A, x2B, N);

    // semantic attention fusion -> out
    attn_kernel<<<divup(N, 4), 256, 0, stream>>>(x1A, x1B, x2A, x2B, A1, ab1, A2, out, N);
}